// Round 15
// baseline (1383.276 us; speedup 1.0000x reference)
//
#include <hip/hip_runtime.h>

#define N0c 100000
#define N1c 20000
#define Ec 320000
#define NBLK ((Ec + 1023) / 1024)   // 313 blocks for length bucketing

typedef _Float16 f16;
typedef _Float16 f16x2 __attribute__((ext_vector_type(2)));

#define LOG2E 1.442695040888963f

__device__ __forceinline__ float sigm(float x) {
    return __builtin_amdgcn_rcpf(1.f + __builtin_amdgcn_exp2f(-LOG2E * x));
}
__device__ __forceinline__ float tanh_(float x) {
    return 2.f * __builtin_amdgcn_rcpf(1.f + __builtin_amdgcn_exp2f(-2.f * LOG2E * x)) - 1.f;
}
__device__ __forceinline__ float dot2(uint w, uint v, float acc) {
#if __has_builtin(__builtin_amdgcn_fdot2)
    return __builtin_amdgcn_fdot2(__builtin_bit_cast(f16x2, w),
                                  __builtin_bit_cast(f16x2, v), acc, false);
#else
    f16x2 a = __builtin_bit_cast(f16x2, w);
    f16x2 b = __builtin_bit_cast(f16x2, v);
    return acc + (float)a[0] * (float)b[0] + (float)a[1] * (float)b[1];
#endif
}
__device__ __forceinline__ uint packh(float a, float b) {
    f16x2 p;
    p[0] = (f16)a;
    p[1] = (f16)b;
    return __builtin_bit_cast(uint, p);
}

// ---------------- length bucketing (deterministic counting sort) -----------
__global__ void count_kernel(const int* __restrict__ elen, int* __restrict__ bc) {
    __shared__ int h[8];
    if (threadIdx.x < 8) h[threadIdx.x] = 0;
    __syncthreads();
    const int base = blockIdx.x * 1024;
    for (int i = threadIdx.x; i < 1024; i += 256) {
        int e = base + i;
        if (e < Ec) atomicAdd(&h[elen[e] - 1], 1);
    }
    __syncthreads();
    if (threadIdx.x < 8) bc[blockIdx.x * 8 + threadIdx.x] = h[threadIdx.x];
}

__global__ void offs_kernel(const int* __restrict__ bc, int* __restrict__ bo) {
    __shared__ int s[NBLK * 8];
    __shared__ int base[8];
    const int tid = threadIdx.x;
    for (int i = tid; i < NBLK * 8; i += 256) s[i] = bc[i];
    __syncthreads();
    if (tid == 0) {
        int tot[8];
        for (int b = 0; b < 8; ++b) {
            int t = 0;
            for (int blk = 0; blk < NBLK; ++blk) t += s[blk * 8 + b];
            tot[b] = t;
        }
        int run = 0;
        for (int b = 0; b < 8; ++b) { base[b] = run; run += tot[b]; }
    }
    __syncthreads();
    if (tid < 8) {
        int run = base[tid];
        for (int blk = 0; blk < NBLK; ++blk) {
            int t = s[blk * 8 + tid];
            s[blk * 8 + tid] = run;
            run += t;
        }
    }
    __syncthreads();
    for (int i = tid; i < NBLK * 8; i += 256) bo[i] = s[i];
}

__global__ void scatter2_kernel(const int* __restrict__ elen, const int* __restrict__ bo,
                                int* __restrict__ lperm, int* __restrict__ lenq) {
    __shared__ int cnt[256][9];
    const int tid = threadIdx.x;
    const int base = blockIdx.x * 1024 + tid * 4;
    int lens[4];
    int lc0 = 0, lc1 = 0, lc2 = 0, lc3 = 0, lc4 = 0, lc5 = 0, lc6 = 0, lc7 = 0;
    #pragma unroll
    for (int j = 0; j < 4; ++j) {
        int e = base + j;
        int l = (e < Ec) ? elen[e] - 1 : -1;
        lens[j] = l;
        lc0 += (l == 0); lc1 += (l == 1); lc2 += (l == 2); lc3 += (l == 3);
        lc4 += (l == 4); lc5 += (l == 5); lc6 += (l == 6); lc7 += (l == 7);
    }
    cnt[tid][0] = lc0; cnt[tid][1] = lc1; cnt[tid][2] = lc2; cnt[tid][3] = lc3;
    cnt[tid][4] = lc4; cnt[tid][5] = lc5; cnt[tid][6] = lc6; cnt[tid][7] = lc7;
    __syncthreads();
    if (tid < 8) {
        int run = bo[blockIdx.x * 8 + tid];
        for (int i = 0; i < 256; ++i) {
            int t = cnt[i][tid];
            cnt[i][tid] = run;
            run += t;
        }
    }
    __syncthreads();
    #pragma unroll
    for (int b = 0; b < 8; ++b) {
        int p = cnt[tid][b];
        #pragma unroll
        for (int j = 0; j < 4; ++j) {
            if (lens[j] == b) { lperm[p] = base + j; lenq[p] = b + 1; ++p; }
        }
    }
}

// ---------------- dst bucketing (for node segment-sum) ---------------------
__global__ void dhist_kernel(const int* __restrict__ dst, int* __restrict__ hist) {
    int e = blockIdx.x * blockDim.x + threadIdx.x;
    if (e < Ec) atomicAdd(&hist[dst[e]], 1);
}

__global__ void dscan_kernel(int* __restrict__ hist) {
    __shared__ int s[N1c];
    __shared__ int psum[256];
    const int tid = threadIdx.x;
    const int CH = (N1c + 255) / 256;
    for (int i = tid; i < N1c; i += 256) s[i] = hist[i];
    __syncthreads();
    int loc = 0;
    #pragma unroll 1
    for (int j = 0; j < CH; ++j) {
        int i = tid * CH + j;
        if (i < N1c) loc += s[i];
    }
    psum[tid] = loc;
    __syncthreads();
    if (tid == 0) {
        int run = 0;
        for (int t = 0; t < 256; ++t) { int v = psum[t]; psum[t] = run; run += v; }
    }
    __syncthreads();
    int run = psum[tid];
    #pragma unroll 1
    for (int j = 0; j < CH; ++j) {
        int i = tid * CH + j;
        if (i < N1c) { int v = s[i]; s[i] = run; run += v; }
    }
    __syncthreads();
    for (int i = tid; i < N1c; i += 256) hist[i] = s[i];
}

__global__ void dscatter_kernel(const int* __restrict__ dst, int* __restrict__ cursor,
                                int* __restrict__ perm) {
    int e = blockIdx.x * blockDim.x + threadIdx.x;
    if (e < Ec) {
        int pos = atomicAdd(&cursor[dst[e]], 1);
        perm[pos] = e;
    }
}

// ---------------- MLP weight prep (eW^T packed pairs, per-lane) ------------
__global__ void wprep_kernel(const float* __restrict__ eW, uint* __restrict__ ewc) {
    int idx = blockIdx.x * 256 + threadIdx.x;
    if (idx < 24 * 256) {
        int c4 = idx >> 8, l = (idx >> 2) & 63, i = idx & 3;
        int cp = c4 * 4 + i;
        ewc[idx] = packh(eW[(2 * cp) * 64 + l], eW[(2 * cp + 1) * 64 + l]);
    }
}

// ---------------- X pre-pack: Xpk[e][t][8] uint (f16 pairs) ----------------
__global__ void xprep_kernel(const float* __restrict__ ef, const float* __restrict__ st,
                             uint* __restrict__ Xpk) {
    int idx = blockIdx.x * 256 + threadIdx.x;   // e*8 + t
    int e = idx >> 3, t = idx & 7;
    float v[16];
    #pragma unroll
    for (int f = 0; f < 15; ++f) v[f] = ef[(size_t)e * 120 + t * 15 + f];
    v[15] = st[(size_t)e * 8 + t];
    uint* dst = Xpk + (size_t)idx * 8;
    #pragma unroll
    for (int j = 0; j < 8; ++j) dst[j] = packh(v[2 * j], v[2 * j + 1]);
}

// ---------------- LSTM: lane=(edge, quarter), LDS weights + LDS h-exchange -
// Wave = 16 edges x 4 unit-quarters. Per-lane regs: hall[32] pairs (reloaded
// from hT each step), cf[16] f32 (own units, static idx). h_new written
// straight to per-wave hT[16][72] (ds_write_b16) -> no hown/own8/shfl.
// Weight rows staggered (R14 layout, conflict-free 4-addr broadcast).
// hT rows 144 B -> eo bank stride 4, eo/eo+8 alias 2-way (free).

__device__ __forceinline__ float gate_full(const char* row, const uint* hall,
                                           const uint* xv, float acc) {
    const uint4* W = (const uint4*)row;
    #pragma unroll
    for (int b = 0; b < 8; ++b) {
        uint4 w = W[b];
        acc = dot2(w.x, hall[b * 4 + 0], acc);
        acc = dot2(w.y, hall[b * 4 + 1], acc);
        acc = dot2(w.z, hall[b * 4 + 2], acc);
        acc = dot2(w.w, hall[b * 4 + 3], acc);
    }
    #pragma unroll
    for (int b = 0; b < 2; ++b) {
        uint4 w = W[8 + b];
        acc = dot2(w.x, xv[b * 4 + 0], acc);
        acc = dot2(w.y, xv[b * 4 + 1], acc);
        acc = dot2(w.z, xv[b * 4 + 2], acc);
        acc = dot2(w.w, xv[b * 4 + 3], acc);
    }
    return acc;
}
__device__ __forceinline__ float gate_x(const char* row, const uint* xv, float acc) {
    const uint4* W = (const uint4*)row;
    #pragma unroll
    for (int b = 0; b < 2; ++b) {
        uint4 w = W[8 + b];
        acc = dot2(w.x, xv[b * 4 + 0], acc);
        acc = dot2(w.y, xv[b * 4 + 1], acc);
        acc = dot2(w.z, xv[b * 4 + 2], acc);
        acc = dot2(w.w, xv[b * 4 + 3], acc);
    }
    return acc;
}

__global__ __launch_bounds__(512)
void lstm_q_kernel(const float* __restrict__ Whh, const float* __restrict__ Wih,
                   const float* __restrict__ lb, const uint* __restrict__ Xpk,
                   const int* __restrict__ lperm, const int* __restrict__ lenq,
                   f16* __restrict__ hb)
{
    __shared__ __align__(16) uint wL[11296];    // 45.2 KB staggered weight rows
    __shared__ float bL[256];                   // 1 KB
    __shared__ __align__(16) f16 hT[8][16 * 72];// 18.4 KB: per-wave h tiles

    const int tid = threadIdx.x;
    for (int idx = tid; idx < 256 * 40; idx += 512) {
        int gm = idx / 40, j2 = idx - gm * 40;
        float w0, w1;
        if (j2 < 32) {
            w0 = Whh[(2 * j2) * 256 + gm];
            w1 = Whh[(2 * j2 + 1) * 256 + gm];
        } else {
            int k = j2 - 32;
            w0 = Wih[(2 * k) * 256 + gm];
            w1 = Wih[(2 * k + 1) * 256 + gm];
        }
        wL[gm * 44 + ((gm >> 4) & 3) * 4 + j2] = packh(w0, w1);
    }
    if (tid < 256) bL[tid] = lb[tid];
    __syncthreads();

    const int lane = tid & 63;
    const int wv = tid >> 6;
    const int q = lane >> 4;     // unit quarter
    const int eo = lane & 15;    // edge within tile

    const char* wb = (const char*)wL + q * (16 * 176 + 16);
    const float* bq = bL + q * 16;
    f16* hrow = hT[wv] + eo * 72;        // own edge's h row (all 64 units)
    f16* hwr = hrow + q * 16;            // own quarter slot

    for (int tile = blockIdx.x * 8 + wv; tile < Ec / 16; tile += gridDim.x * 8) {
        const int i = tile * 16 + eo;
        const int oe = lperm[i];
        const int mylen = lenq[i];
        int tmax = mylen;
        tmax = max(tmax, __shfl_xor(tmax, 1));
        tmax = max(tmax, __shfl_xor(tmax, 2));
        tmax = max(tmax, __shfl_xor(tmax, 4));
        tmax = max(tmax, __shfl_xor(tmax, 8));

        const uint* xr = Xpk + (size_t)oe * 64;

        uint hall[32];
        float cf[16];
        uint xv[8];

        // ---- t = 0 (h == 0): x-part only ----
        {
            uint4 x0 = *(const uint4*)(xr);
            uint4 x1 = *(const uint4*)(xr + 4);
            xv[0] = x0.x; xv[1] = x0.y; xv[2] = x0.z; xv[3] = x0.w;
            xv[4] = x1.x; xv[5] = x1.y; xv[6] = x1.z; xv[7] = x1.w;
            #pragma unroll
            for (int ul = 0; ul < 16; ++ul) {
                float aI = gate_x(wb + (0 * 64 + ul) * 176, xv, bq[0 * 64 + ul]);
                float aG = gate_x(wb + (2 * 64 + ul) * 176, xv, bq[2 * 64 + ul]);
                float aO = gate_x(wb + (3 * 64 + ul) * 176, xv, bq[3 * 64 + ul]);
                float ig = sigm(aI), gg = tanh_(aG), og = sigm(aO);
                float cn = ig * gg;          // c0 = 0
                float hn = og * tanh_(cn);
                cf[ul] = cn;
                hwr[ul] = (f16)hn;           // ds_write_b16 into hT
            }
            #pragma unroll
            for (int k = 0; k < 8; ++k) {
                uint4 v = *(const uint4*)(hrow + k * 8);
                hall[4 * k + 0] = v.x; hall[4 * k + 1] = v.y;
                hall[4 * k + 2] = v.z; hall[4 * k + 3] = v.w;
            }
        }

        // ---- t = 1 .. tmax-1 ----
        for (int t = 1; t < tmax; ++t) {
            uint4 x0 = *(const uint4*)(xr + t * 8);
            uint4 x1 = *(const uint4*)(xr + t * 8 + 4);
            xv[0] = x0.x; xv[1] = x0.y; xv[2] = x0.z; xv[3] = x0.w;
            xv[4] = x1.x; xv[5] = x1.y; xv[6] = x1.z; xv[7] = x1.w;
            const bool live = (t < mylen);
            #pragma unroll
            for (int ul = 0; ul < 16; ++ul) {
                float aI = gate_full(wb + (0 * 64 + ul) * 176, hall, xv, bq[0 * 64 + ul]);
                float aF = gate_full(wb + (1 * 64 + ul) * 176, hall, xv, bq[1 * 64 + ul]);
                float aG = gate_full(wb + (2 * 64 + ul) * 176, hall, xv, bq[2 * 64 + ul]);
                float aO = gate_full(wb + (3 * 64 + ul) * 176, hall, xv, bq[3 * 64 + ul]);
                float ig = sigm(aI), fg = sigm(aF), gg = tanh_(aG), og = sigm(aO);
                float cn = fg * cf[ul] + ig * gg;
                float hn = og * tanh_(cn);
                if (live) {
                    cf[ul] = cn;
                    hwr[ul] = (f16)hn;       // exec-masked ds_write_b16
                }
            }
            if (t + 1 < tmax) {
                #pragma unroll
                for (int k = 0; k < 8; ++k) {
                    uint4 v = *(const uint4*)(hrow + k * 8);
                    hall[4 * k + 0] = v.x; hall[4 * k + 1] = v.y;
                    hall[4 * k + 2] = v.z; hall[4 * k + 3] = v.w;
                }
            }
        }

        // ---- write own quarter of final h to hb[oe][units] ----
        {
            const uint4* op = (const uint4*)(hwr);
            uint4 o0 = op[0];
            uint4 o1 = op[1];
            uint4* hp = (uint4*)(hb + (size_t)oe * 64 + q * 16);
            hp[0] = o0;
            hp[1] = o1;
        }
    }
}

// ---------------- MLP: wave-per-edge, eW in registers, f16 dot2 ------------
__global__ __launch_bounds__(256, 2)
void mlp_kernel(const float* __restrict__ nf, const float* __restrict__ pw,
                const uint4* __restrict__ ewc4, const float* __restrict__ ebias,
                const int* __restrict__ src, const f16* __restrict__ hb,
                f16* __restrict__ mbuf)
{
    __shared__ __align__(16) f16 sCat[4][192];
    const int lane = threadIdx.x & 63;
    const int wv = threadIdx.x >> 6;

    uint ew[24][4];
    #pragma unroll
    for (int i = 0; i < 24; ++i) {
        uint4 v = ewc4[i * 64 + lane];
        ew[i][0] = v.x; ew[i][1] = v.y; ew[i][2] = v.z; ew[i][3] = v.w;
    }
    const float pwl = pw[lane], pwh = pw[64 + lane];
    const float ebl = ebias[lane];

    f16* myCat = sCat[wv];
    const int wid = blockIdx.x * 4 + wv;
    for (int e = wid; e < Ec; e += 2048) {
        const int s = src[e];
        float hs0 = nf[(size_t)s * 128 + lane];
        float hs1 = nf[(size_t)s * 128 + 64 + lane];
        float part = hs0 * pwl + hs1 * pwh;
        #pragma unroll
        for (int off = 32; off; off >>= 1) part += __shfl_xor(part, off);
        float he = (float)hb[(size_t)e * 64 + lane];
        myCat[lane] = (f16)(hs0 - part * pwl);
        myCat[64 + lane] = (f16)(hs1 - part * pwh);
        myCat[128 + lane] = (f16)he;
        const uint4* cp = (const uint4*)myCat;
        float m0 = 0.f, m1 = 0.f, m2 = 0.f, m3 = 0.f;
        #pragma unroll
        for (int i = 0; i < 24; ++i) {
            uint4 qv = cp[i];
            m0 = dot2(ew[i][0], qv.x, m0);
            m1 = dot2(ew[i][1], qv.y, m1);
            m2 = dot2(ew[i][2], qv.z, m2);
            m3 = dot2(ew[i][3], qv.w, m3);
        }
        float m = fmaxf(m0 + m1 + m2 + m3 + ebl, 0.f);
        mbuf[(size_t)e * 64 + lane] = (f16)m;
    }
}

// ---------------- Node kernel: segment-sum of m + node math ----------------
#define NB_WAVES 8
#define NB_THREADS (NB_WAVES * 64)
__global__ __launch_bounds__(NB_THREADS, 1)
void node_kernel(const float* __restrict__ nf,
                 const float* __restrict__ sgn,
                 const float* __restrict__ eW,
                 const float* __restrict__ ebias,
                 const float* __restrict__ nW,
                 const float* __restrict__ nbias,
                 const float* __restrict__ fcW,
                 const float* __restrict__ fcb,
                 const int* __restrict__ lnid,
                 const int* __restrict__ hist,
                 const int* __restrict__ perm,
                 const f16* __restrict__ m,
                 float* __restrict__ out,
                 int nWavesTotal)
{
    __shared__ float sEW[128 * 64];
    __shared__ float sNW[192 * 64];
    __shared__ float sFC[64 * 16];
    __shared__ float sCat[NB_WAVES][192];
    __shared__ float sAct[NB_WAVES][64];

    const int tid = threadIdx.x;
    for (int idx = tid; idx < 128 * 64; idx += NB_THREADS) sEW[idx] = eW[idx];
    for (int idx = tid; idx < 192 * 64; idx += NB_THREADS) sNW[idx] = nW[idx];
    for (int idx = tid; idx < 64 * 16; idx += NB_THREADS) sFC[idx] = fcW[idx];
    __syncthreads();

    const int lane = tid & 63;
    const int wv = tid >> 6;
    const int gwave = blockIdx.x * NB_WAVES + wv;

    const float ebv = ebias[lane];
    const float nbv = nbias[lane];
    const float fcbv = (lane < 16) ? fcb[lane] : 0.f;

    for (int n = gwave; n < N1c; n += nWavesTotal) {
        const int nid = lnid[n];
        float sh0 = nf[(size_t)nid * 128 + lane];
        float sh1 = nf[(size_t)nid * 128 + 64 + lane];
        sCat[wv][lane] = sh0;
        sCat[wv][64 + lane] = sh1;

        float tmp = ebv;
        #pragma unroll 8
        for (int cc = 0; cc < 128; ++cc) tmp += sCat[wv][cc] * sEW[cc * 64 + lane];

        const int o0 = (n == 0) ? 0 : hist[n - 1];
        const int o1 = hist[n];
        float av = 0.f;
        for (int base = o0; base < o1; base += 64) {
            int cnt = min(64, o1 - base);
            int pk = (lane < cnt) ? perm[base + lane] : 0;
            for (int j = 0; j < cnt; ++j) {
                int pe = __shfl(pk, j);
                av += (float)m[(size_t)pe * 64 + lane];
            }
        }

        float hu = (av - tmp) * sgn[n];
        sCat[wv][128 + lane] = hu;

        float acc = nbv;
        #pragma unroll 8
        for (int cc = 0; cc < 192; ++cc) acc += sCat[wv][cc] * sNW[cc * 64 + lane];
        acc = fmaxf(acc, 0.f);
        sAct[wv][lane] = acc;

        if (lane < 16) {
            float o = fcbv;
            #pragma unroll
            for (int j = 0; j < 64; ++j) o += sAct[wv][j] * sFC[j * 16 + lane];
            out[(size_t)n * 16 + lane] = o;
        }
    }
}

extern "C" void kernel_launch(void* const* d_in, const int* in_sizes, int n_in,
                              void* d_out, int out_size, void* d_ws, size_t ws_size,
                              hipStream_t stream) {
    const float* nf  = (const float*)d_in[0];
    const float* ef  = (const float*)d_in[1];
    const float* st  = (const float*)d_in[2];
    const float* sgn = (const float*)d_in[3];
    const float* pw  = (const float*)d_in[4];
    const float* Wih = (const float*)d_in[5];
    const float* Whh = (const float*)d_in[6];
    const float* lb  = (const float*)d_in[7];
    const float* eW  = (const float*)d_in[8];
    const float* eb  = (const float*)d_in[9];
    const float* nW  = (const float*)d_in[10];
    const float* nb  = (const float*)d_in[11];
    const float* fcW = (const float*)d_in[12];
    const float* fcb = (const float*)d_in[13];
    const int* elen = (const int*)d_in[14];
    const int* src  = (const int*)d_in[15];
    const int* dst  = (const int*)d_in[16];
    const int* lnid = (const int*)d_in[17];

    float* out = (float*)d_out;

    // ws layout (bytes)
    char* base = (char*)d_ws;
    int*  hist  = (int*) (base + 0);           // 80 KB
    int*  dperm = (int*) (base + 81920);       // 1.28 MB -> 1392640
    int*  bc    = (int*) (base + 1392640);     // 16 KB
    int*  bo    = (int*) (base + 1409024);     // 16 KB
    int*  lperm = (int*) (base + 1425408);     // 1.28 MB -> 2736128
    int*  lenq  = (int*) (base + 2736128);     // 1.28 MB -> 4046848
    uint* ewc   = (uint*)(base + 4046848);     // 24.5 KB -> 4079616
    uint* Xpk   = (uint*)(base + 4079616);     // 81.92 MB -> 85999616
    f16*  hb    = (f16*) (base + 85999616);    // 40.96 MB -> 126959616
    f16*  mbuf  = (f16*) (base + 126959616);   // 40.96 MB -> 167919616

    hipMemsetAsync(hist, 0, 81920, stream);

    // length sort (for LSTM tiles)
    count_kernel<<<NBLK, 256, 0, stream>>>(elen, bc);
    offs_kernel<<<1, 256, 0, stream>>>(bc, bo);
    scatter2_kernel<<<NBLK, 256, 0, stream>>>(elen, bo, lperm, lenq);

    // dst sort (for node segment-sum)
    dhist_kernel<<<1250, 256, 0, stream>>>(dst, hist);
    dscan_kernel<<<1, 256, 0, stream>>>(hist);
    dscatter_kernel<<<1250, 256, 0, stream>>>(dst, hist, dperm);

    wprep_kernel<<<24, 256, 0, stream>>>(eW, ewc);
    xprep_kernel<<<10000, 256, 0, stream>>>(ef, st, Xpk);

    lstm_q_kernel<<<1250, 512, 0, stream>>>(Whh, Wih, lb, Xpk, lperm, lenq, hb);

    mlp_kernel<<<512, 256, 0, stream>>>(nf, pw, (const uint4*)ewc, eb, src, hb, mbuf);

    node_kernel<<<512, NB_THREADS, 0, stream>>>(
        nf, sgn, eW, eb, nW, nb, fcW, fcb, lnid, hist, dperm, mbuf, out,
        512 * NB_WAVES);
}

// Round 16
// 1095.819 us; speedup vs baseline: 1.2623x; 1.2623x over previous
//
#include <hip/hip_runtime.h>

#define N0c 100000
#define N1c 20000
#define Ec 320000

typedef _Float16 f16;
typedef _Float16 f16x2 __attribute__((ext_vector_type(2)));

#define LOG2E 1.442695040888963f

__device__ __forceinline__ float sigm(float x) {
    return __builtin_amdgcn_rcpf(1.f + __builtin_amdgcn_exp2f(-LOG2E * x));
}
__device__ __forceinline__ float tanh_(float x) {
    return 2.f * __builtin_amdgcn_rcpf(1.f + __builtin_amdgcn_exp2f(-2.f * LOG2E * x)) - 1.f;
}
__device__ __forceinline__ float dot2(uint w, uint v, float acc) {
#if __has_builtin(__builtin_amdgcn_fdot2)
    return __builtin_amdgcn_fdot2(__builtin_bit_cast(f16x2, w),
                                  __builtin_bit_cast(f16x2, v), acc, false);
#else
    f16x2 a = __builtin_bit_cast(f16x2, w);
    f16x2 b = __builtin_bit_cast(f16x2, v);
    return acc + (float)a[0] * (float)b[0] + (float)a[1] * (float)b[1];
#endif
}
__device__ __forceinline__ uint packh(float a, float b) {
    f16x2 p;
    p[0] = (f16)a;
    p[1] = (f16)b;
    return __builtin_bit_cast(uint, p);
}

// ---------------- bucketing by dst: hist -> scan -> scatter ----------------
__global__ void dhist_kernel(const int* __restrict__ dst, int* __restrict__ hist) {
    int e = blockIdx.x * blockDim.x + threadIdx.x;
    if (e < Ec) atomicAdd(&hist[dst[e]], 1);
}

__global__ void dscan_kernel(int* __restrict__ hist) {
    __shared__ int s[N1c];
    __shared__ int psum[256];
    const int tid = threadIdx.x;
    const int CH = (N1c + 255) / 256;
    for (int i = tid; i < N1c; i += 256) s[i] = hist[i];
    __syncthreads();
    int loc = 0;
    #pragma unroll 1
    for (int j = 0; j < CH; ++j) {
        int i = tid * CH + j;
        if (i < N1c) loc += s[i];
    }
    psum[tid] = loc;
    __syncthreads();
    if (tid == 0) {
        int run = 0;
        for (int t = 0; t < 256; ++t) { int v = psum[t]; psum[t] = run; run += v; }
    }
    __syncthreads();
    int run = psum[tid];
    #pragma unroll 1
    for (int j = 0; j < CH; ++j) {
        int i = tid * CH + j;
        if (i < N1c) { int v = s[i]; s[i] = run; run += v; }
    }
    __syncthreads();
    for (int i = tid; i < N1c; i += 256) hist[i] = s[i];
}

__global__ void dscatter_kernel(const int* __restrict__ dst, int* __restrict__ cursor,
                                int* __restrict__ perm) {
    int e = blockIdx.x * blockDim.x + threadIdx.x;
    if (e < Ec) {
        int pos = atomicAdd(&cursor[dst[e]], 1);
        perm[pos] = e;
    }
}

// ---------------- weight prep: per-lane packed f16 pair layouts ------------
__global__ void wprep_kernel(const float* __restrict__ Whh, const float* __restrict__ Wih,
                             const float* __restrict__ eW,
                             uint* __restrict__ wpk, uint* __restrict__ ewc) {
    int idx = blockIdx.x * 256 + threadIdx.x;
    if (idx < 40 * 256) {
        int r4 = idx >> 8, l = (idx >> 2) & 63, i = idx & 3;
        uint v;
        if (r4 < 32)
            v = packh(Whh[(2 * r4) * 256 + i * 64 + l], Whh[(2 * r4 + 1) * 256 + i * 64 + l]);
        else {
            int kp = r4 - 32;
            v = packh(Wih[(2 * kp) * 256 + i * 64 + l], Wih[(2 * kp + 1) * 256 + i * 64 + l]);
        }
        wpk[idx] = v;
    }
    if (idx < 24 * 256) {
        int c4 = idx >> 8, l = (idx >> 2) & 63, i = idx & 3;
        int cp = c4 * 4 + i;
        ewc[idx] = packh(eW[(2 * cp) * 64 + l], eW[(2 * cp + 1) * 64 + l]);
    }
}

// ---------------- X pre-pack: Xpk[e][t][8] uint (f16 pairs) ----------------
__global__ void xprep_kernel(const float* __restrict__ ef, const float* __restrict__ st,
                             uint* __restrict__ Xpk) {
    int idx = blockIdx.x * 256 + threadIdx.x;   // e*8 + t
    int e = idx >> 3, t = idx & 7;
    float v[16];
    #pragma unroll
    for (int f = 0; f < 15; ++f) v[f] = ef[(size_t)e * 120 + t * 15 + f];
    v[15] = st[(size_t)e * 8 + t];
    uint* dst = Xpk + (size_t)idx * 8;
    #pragma unroll
    for (int j = 0; j < 8; ++j) dst[j] = packh(v[2 * j], v[2 * j + 1]);
}

// ---------------- LSTM: wave-per-edge, weights in registers, f16 dot2 ------
#define XD(K, XV) \
    a0 = dot2(wi[K][0], XV, a0); a1 = dot2(wi[K][1], XV, a1); \
    a2 = dot2(wi[K][2], XV, a2); a3 = dot2(wi[K][3], XV, a3);
#define HD(JP, QV) \
    a0 = dot2(wh[JP][0], QV, a0); a1 = dot2(wh[JP][1], QV, a1); \
    a2 = dot2(wh[JP][2], QV, a2); a3 = dot2(wh[JP][3], QV, a3);

// R12/R13 lessons: __launch_bounds__ 2nd arg is a MIN waves/EU -> does not
// change the allocator's occupancy target (VGPR stayed 116); asm pins get
// copied to scratch (VGPR 96, +50 us). The allocator's budget is driven by
// the MAX waves/EU: amdgpu_waves_per_eu(2,2) declares exactly 2 waves/EU
// (= R11's measured occupancy), giving a 256-VGPR budget so the 160 weight
// words + ~60 live state fit register-resident with no occupancy loss.
__global__ __attribute__((amdgpu_flat_work_group_size(256, 256), amdgpu_waves_per_eu(2, 2)))
void lstm_kernel(const uint4* __restrict__ wpk4, const float* __restrict__ lb,
                 const uint* __restrict__ Xpk, const int* __restrict__ elen,
                 f16* __restrict__ hb)
{
    __shared__ __align__(16) f16 sH[4][64];
    const int lane = threadIdx.x & 63;
    const int wv = threadIdx.x >> 6;

    uint wh[32][4];
    uint wi[8][4];
    #pragma unroll
    for (int r4 = 0; r4 < 32; ++r4) {
        uint4 v = wpk4[r4 * 64 + lane];
        wh[r4][0] = v.x; wh[r4][1] = v.y; wh[r4][2] = v.z; wh[r4][3] = v.w;
    }
    #pragma unroll
    for (int k4 = 0; k4 < 8; ++k4) {
        uint4 v = wpk4[(32 + k4) * 64 + lane];
        wi[k4][0] = v.x; wi[k4][1] = v.y; wi[k4][2] = v.z; wi[k4][3] = v.w;
    }
    const float b0 = lb[lane], b1 = lb[64 + lane], b2 = lb[128 + lane], b3 = lb[192 + lane];

    f16* myH = sH[wv];
    const int wid = blockIdx.x * 4 + wv;
    for (int e = wid; e < Ec; e += 2048) {
        const int len = elen[e];
        const uint* xr = Xpk + (size_t)e * 64;
        uint4 xa = *(const uint4*)(xr);
        uint4 xb = *(const uint4*)(xr + 4);
        float h = 0.f, cc = 0.f;
        for (int t = 0; t < len; ++t) {
            float a0 = b0, a1 = b1, a2 = b2, a3 = b3;
            XD(0, xa.x) XD(1, xa.y) XD(2, xa.z) XD(3, xa.w)
            XD(4, xb.x) XD(5, xb.y) XD(6, xb.z) XD(7, xb.w)
            // prefetch next step's x (clamped; row always valid)
            {
                int tn = (t < 7) ? t + 1 : 7;
                xa = *(const uint4*)(xr + tn * 8);
                xb = *(const uint4*)(xr + tn * 8 + 4);
            }
            if (t > 0) {
                const uint4* hp = (const uint4*)myH;
                #pragma unroll
                for (int i = 0; i < 8; ++i) {
                    uint4 q = hp[i];
                    HD(4 * i + 0, q.x)
                    HD(4 * i + 1, q.y)
                    HD(4 * i + 2, q.z)
                    HD(4 * i + 3, q.w)
                }
            }
            float ig = sigm(a0);
            float fg = sigm(a1);
            float gg = tanh_(a2);
            float og = sigm(a3);
            cc = fg * cc + ig * gg;
            h = og * tanh_(cc);
            myH[lane] = (f16)h;   // next step's broadcast source (same-wave, no barrier)
        }
        hb[(size_t)e * 64 + lane] = (f16)h;
    }
}

// ---------------- MLP: wave-per-edge, eW in registers, f16 dot2 ------------
__global__ __launch_bounds__(256, 2)
void mlp_kernel(const float* __restrict__ nf, const float* __restrict__ pw,
                const uint4* __restrict__ ewc4, const float* __restrict__ ebias,
                const int* __restrict__ src, const f16* __restrict__ hb,
                f16* __restrict__ mbuf)
{
    __shared__ __align__(16) f16 sCat[4][192];
    const int lane = threadIdx.x & 63;
    const int wv = threadIdx.x >> 6;

    uint ew[24][4];
    #pragma unroll
    for (int i = 0; i < 24; ++i) {
        uint4 v = ewc4[i * 64 + lane];
        ew[i][0] = v.x; ew[i][1] = v.y; ew[i][2] = v.z; ew[i][3] = v.w;
    }
    const float pwl = pw[lane], pwh = pw[64 + lane];
    const float ebl = ebias[lane];

    f16* myCat = sCat[wv];
    const int wid = blockIdx.x * 4 + wv;
    for (int e = wid; e < Ec; e += 2048) {
        const int s = src[e];
        float hs0 = nf[(size_t)s * 128 + lane];
        float hs1 = nf[(size_t)s * 128 + 64 + lane];
        float part = hs0 * pwl + hs1 * pwh;
        #pragma unroll
        for (int off = 32; off; off >>= 1) part += __shfl_xor(part, off);
        float he = (float)hb[(size_t)e * 64 + lane];
        myCat[lane] = (f16)(hs0 - part * pwl);
        myCat[64 + lane] = (f16)(hs1 - part * pwh);
        myCat[128 + lane] = (f16)he;
        const uint4* cp = (const uint4*)myCat;
        float m0 = 0.f, m1 = 0.f, m2 = 0.f, m3 = 0.f;
        #pragma unroll
        for (int i = 0; i < 24; ++i) {
            uint4 q = cp[i];
            m0 = dot2(ew[i][0], q.x, m0);
            m1 = dot2(ew[i][1], q.y, m1);
            m2 = dot2(ew[i][2], q.z, m2);
            m3 = dot2(ew[i][3], q.w, m3);
        }
        float m = fmaxf(m0 + m1 + m2 + m3 + ebl, 0.f);
        mbuf[(size_t)e * 64 + lane] = (f16)m;
    }
}

// ---------------- Node kernel: segment-sum of m + node math ----------------
#define NB_WAVES 8
#define NB_THREADS (NB_WAVES * 64)
__global__ __launch_bounds__(NB_THREADS, 1)
void node_kernel(const float* __restrict__ nf,
                 const float* __restrict__ sgn,
                 const float* __restrict__ eW,
                 const float* __restrict__ ebias,
                 const float* __restrict__ nW,
                 const float* __restrict__ nbias,
                 const float* __restrict__ fcW,
                 const float* __restrict__ fcb,
                 const int* __restrict__ lnid,
                 const int* __restrict__ hist,
                 const int* __restrict__ perm,
                 const f16* __restrict__ m,
                 float* __restrict__ out,
                 int nWavesTotal)
{
    __shared__ float sEW[128 * 64];
    __shared__ float sNW[192 * 64];
    __shared__ float sFC[64 * 16];
    __shared__ float sCat[NB_WAVES][192];
    __shared__ float sAct[NB_WAVES][64];

    const int tid = threadIdx.x;
    for (int idx = tid; idx < 128 * 64; idx += NB_THREADS) sEW[idx] = eW[idx];
    for (int idx = tid; idx < 192 * 64; idx += NB_THREADS) sNW[idx] = nW[idx];
    for (int idx = tid; idx < 64 * 16; idx += NB_THREADS) sFC[idx] = fcW[idx];
    __syncthreads();

    const int lane = tid & 63;
    const int wv = tid >> 6;
    const int gwave = blockIdx.x * NB_WAVES + wv;

    const float ebv = ebias[lane];
    const float nbv = nbias[lane];
    const float fcbv = (lane < 16) ? fcb[lane] : 0.f;

    for (int n = gwave; n < N1c; n += nWavesTotal) {
        const int nid = lnid[n];
        float sh0 = nf[(size_t)nid * 128 + lane];
        float sh1 = nf[(size_t)nid * 128 + 64 + lane];
        sCat[wv][lane] = sh0;
        sCat[wv][64 + lane] = sh1;

        float tmp = ebv;
        #pragma unroll 8
        for (int cc = 0; cc < 128; ++cc) tmp += sCat[wv][cc] * sEW[cc * 64 + lane];

        const int o0 = (n == 0) ? 0 : hist[n - 1];
        const int o1 = hist[n];
        float av = 0.f;
        for (int base = o0; base < o1; base += 64) {
            int cnt = min(64, o1 - base);
            int pk = (lane < cnt) ? perm[base + lane] : 0;
            for (int j = 0; j < cnt; ++j) {
                int pe = __shfl(pk, j);
                av += (float)m[(size_t)pe * 64 + lane];
            }
        }

        float hu = (av - tmp) * sgn[n];
        sCat[wv][128 + lane] = hu;

        float acc = nbv;
        #pragma unroll 8
        for (int cc = 0; cc < 192; ++cc) acc += sCat[wv][cc] * sNW[cc * 64 + lane];
        acc = fmaxf(acc, 0.f);
        sAct[wv][lane] = acc;

        if (lane < 16) {
            float o = fcbv;
            #pragma unroll
            for (int j = 0; j < 64; ++j) o += sAct[wv][j] * sFC[j * 16 + lane];
            out[(size_t)n * 16 + lane] = o;
        }
    }
}

extern "C" void kernel_launch(void* const* d_in, const int* in_sizes, int n_in,
                              void* d_out, int out_size, void* d_ws, size_t ws_size,
                              hipStream_t stream) {
    const float* nf  = (const float*)d_in[0];
    const float* ef  = (const float*)d_in[1];
    const float* st  = (const float*)d_in[2];
    const float* sgn = (const float*)d_in[3];
    const float* pw  = (const float*)d_in[4];
    const float* Wih = (const float*)d_in[5];
    const float* Whh = (const float*)d_in[6];
    const float* lb  = (const float*)d_in[7];
    const float* eW  = (const float*)d_in[8];
    const float* eb  = (const float*)d_in[9];
    const float* nW  = (const float*)d_in[10];
    const float* nb  = (const float*)d_in[11];
    const float* fcW = (const float*)d_in[12];
    const float* fcb = (const float*)d_in[13];
    const int* elen = (const int*)d_in[14];
    const int* src  = (const int*)d_in[15];
    const int* dst  = (const int*)d_in[16];
    const int* lnid = (const int*)d_in[17];

    float* out = (float*)d_out;

    // ws layout (bytes)
    char* base = (char*)d_ws;
    int*  hist = (int*) (base + 0);           // 80 KB
    int*  perm = (int*) (base + 81920);       // 1.28 MB (pad 1310720)
    uint* wpk  = (uint*)(base + 1392640);     // 40 KB (pad 65536)
    uint* ewc  = (uint*)(base + 1458176);     // 24.5 KB (pad 32768)
    uint* Xpk  = (uint*)(base + 1490944);     // 81.92 MB
    f16*  hb   = (f16*) (base + 83410944);    // 40.96 MB
    f16*  mbuf = (f16*) (base + 124370944);   // 40.96 MB (end ~165.3 MB)

    hipMemsetAsync(hist, 0, 81920, stream);

    dhist_kernel<<<1250, 256, 0, stream>>>(dst, hist);
    dscan_kernel<<<1, 256, 0, stream>>>(hist);
    dscatter_kernel<<<1250, 256, 0, stream>>>(dst, hist, perm);

    wprep_kernel<<<40, 256, 0, stream>>>(Whh, Wih, eW, wpk, ewc);
    xprep_kernel<<<10000, 256, 0, stream>>>(ef, st, Xpk);

    lstm_kernel<<<512, 256, 0, stream>>>((const uint4*)wpk, lb, Xpk, elen, hb);
    mlp_kernel<<<512, 256, 0, stream>>>(nf, pw, (const uint4*)ewc, eb, src, hb, mbuf);

    node_kernel<<<512, NB_THREADS, 0, stream>>>(
        nf, sgn, eW, eb, nW, nb, fcW, fcb, lnid, hist, perm, mbuf, out,
        512 * NB_WAVES);
}

// Round 17
// 908.991 us; speedup vs baseline: 1.5218x; 1.2055x over previous
//
#include <hip/hip_runtime.h>

#define N0c 100000
#define N1c 20000
#define Ec 320000
#define NBLK ((Ec + 1023) / 1024)

typedef _Float16 f16;
typedef _Float16 f16x2 __attribute__((ext_vector_type(2)));

#define LOG2E 1.442695040888963f

__device__ __forceinline__ float sigm(float x) {
    return __builtin_amdgcn_rcpf(1.f + __builtin_amdgcn_exp2f(-LOG2E * x));
}
__device__ __forceinline__ float tanh_(float x) {
    return 2.f * __builtin_amdgcn_rcpf(1.f + __builtin_amdgcn_exp2f(-2.f * LOG2E * x)) - 1.f;
}
__device__ __forceinline__ float dot2(uint w, uint v, float acc) {
#if __has_builtin(__builtin_amdgcn_fdot2)
    return __builtin_amdgcn_fdot2(__builtin_bit_cast(f16x2, w),
                                  __builtin_bit_cast(f16x2, v), acc, false);
#else
    f16x2 a = __builtin_bit_cast(f16x2, w);
    f16x2 b = __builtin_bit_cast(f16x2, v);
    return acc + (float)a[0] * (float)b[0] + (float)a[1] * (float)b[1];
#endif
}
__device__ __forceinline__ uint packh(float a, float b) {
    f16x2 p;
    p[0] = (f16)a;
    p[1] = (f16)b;
    return __builtin_bit_cast(uint, p);
}

// ---------------- length bucketing (deterministic counting sort) -----------
__global__ void count_kernel(const int* __restrict__ elen, int* __restrict__ bc) {
    __shared__ int h[8];
    if (threadIdx.x < 8) h[threadIdx.x] = 0;
    __syncthreads();
    const int base = blockIdx.x * 1024;
    for (int i = threadIdx.x; i < 1024; i += 256) {
        int e = base + i;
        if (e < Ec) atomicAdd(&h[elen[e] - 1], 1);
    }
    __syncthreads();
    if (threadIdx.x < 8) bc[blockIdx.x * 8 + threadIdx.x] = h[threadIdx.x];
}

__global__ void offs_kernel(const int* __restrict__ bc, int* __restrict__ bo) {
    __shared__ int s[NBLK * 8];
    __shared__ int base[8];
    const int tid = threadIdx.x;
    for (int i = tid; i < NBLK * 8; i += 256) s[i] = bc[i];
    __syncthreads();
    if (tid == 0) {
        int tot[8];
        for (int b = 0; b < 8; ++b) {
            int t = 0;
            for (int blk = 0; blk < NBLK; ++blk) t += s[blk * 8 + b];
            tot[b] = t;
        }
        int run = 0;
        for (int b = 0; b < 8; ++b) { base[b] = run; run += tot[b]; }
    }
    __syncthreads();
    if (tid < 8) {
        int run = base[tid];
        for (int blk = 0; blk < NBLK; ++blk) {
            int t = s[blk * 8 + tid];
            s[blk * 8 + tid] = run;
            run += t;
        }
    }
    __syncthreads();
    for (int i = tid; i < NBLK * 8; i += 256) bo[i] = s[i];
}

__global__ void scatter2_kernel(const int* __restrict__ elen, const int* __restrict__ bo,
                                int* __restrict__ lperm, int* __restrict__ lenq) {
    __shared__ int cnt[256][9];
    const int tid = threadIdx.x;
    const int base = blockIdx.x * 1024 + tid * 4;
    int lens[4];
    int lc0 = 0, lc1 = 0, lc2 = 0, lc3 = 0, lc4 = 0, lc5 = 0, lc6 = 0, lc7 = 0;
    #pragma unroll
    for (int j = 0; j < 4; ++j) {
        int e = base + j;
        int l = (e < Ec) ? elen[e] - 1 : -1;
        lens[j] = l;
        lc0 += (l == 0); lc1 += (l == 1); lc2 += (l == 2); lc3 += (l == 3);
        lc4 += (l == 4); lc5 += (l == 5); lc6 += (l == 6); lc7 += (l == 7);
    }
    cnt[tid][0] = lc0; cnt[tid][1] = lc1; cnt[tid][2] = lc2; cnt[tid][3] = lc3;
    cnt[tid][4] = lc4; cnt[tid][5] = lc5; cnt[tid][6] = lc6; cnt[tid][7] = lc7;
    __syncthreads();
    if (tid < 8) {
        int run = bo[blockIdx.x * 8 + tid];
        for (int i = 0; i < 256; ++i) {
            int t = cnt[i][tid];
            cnt[i][tid] = run;
            run += t;
        }
    }
    __syncthreads();
    #pragma unroll
    for (int b = 0; b < 8; ++b) {
        int p = cnt[tid][b];
        #pragma unroll
        for (int j = 0; j < 4; ++j) {
            if (lens[j] == b) { lperm[p] = base + j; lenq[p] = b + 1; ++p; }
        }
    }
}

// ---------------- dst bucketing (for node segment-sum) ---------------------
__global__ void dhist_kernel(const int* __restrict__ dst, int* __restrict__ hist) {
    int e = blockIdx.x * blockDim.x + threadIdx.x;
    if (e < Ec) atomicAdd(&hist[dst[e]], 1);
}

__global__ void dscan_kernel(int* __restrict__ hist) {
    __shared__ int s[N1c];
    __shared__ int psum[256];
    const int tid = threadIdx.x;
    const int CH = (N1c + 255) / 256;
    for (int i = tid; i < N1c; i += 256) s[i] = hist[i];
    __syncthreads();
    int loc = 0;
    #pragma unroll 1
    for (int j = 0; j < CH; ++j) {
        int i = tid * CH + j;
        if (i < N1c) loc += s[i];
    }
    psum[tid] = loc;
    __syncthreads();
    if (tid == 0) {
        int run = 0;
        for (int t = 0; t < 256; ++t) { int v = psum[t]; psum[t] = run; run += v; }
    }
    __syncthreads();
    int run = psum[tid];
    #pragma unroll 1
    for (int j = 0; j < CH; ++j) {
        int i = tid * CH + j;
        if (i < N1c) { int v = s[i]; s[i] = run; run += v; }
    }
    __syncthreads();
    for (int i = tid; i < N1c; i += 256) hist[i] = s[i];
}

__global__ void dscatter_kernel(const int* __restrict__ dst, int* __restrict__ cursor,
                                int* __restrict__ perm) {
    int e = blockIdx.x * blockDim.x + threadIdx.x;
    if (e < Ec) {
        int pos = atomicAdd(&cursor[dst[e]], 1);
        perm[pos] = e;
    }
}

// ---------------- weight prep (unchanged layout from R11) ------------------
__global__ void wprep_kernel(const float* __restrict__ Whh, const float* __restrict__ Wih,
                             const float* __restrict__ eW,
                             uint* __restrict__ wpk, uint* __restrict__ ewc) {
    int idx = blockIdx.x * 256 + threadIdx.x;
    if (idx < 40 * 256) {
        int r4 = idx >> 8, l = (idx >> 2) & 63, i = idx & 3;
        uint v;
        if (r4 < 32)
            v = packh(Whh[(2 * r4) * 256 + i * 64 + l], Whh[(2 * r4 + 1) * 256 + i * 64 + l]);
        else {
            int kp = r4 - 32;
            v = packh(Wih[(2 * kp) * 256 + i * 64 + l], Wih[(2 * kp + 1) * 256 + i * 64 + l]);
        }
        wpk[idx] = v;
    }
    if (idx < 24 * 256) {
        int c4 = idx >> 8, l = (idx >> 2) & 63, i = idx & 3;
        int cp = c4 * 4 + i;
        ewc[idx] = packh(eW[(2 * cp) * 64 + l], eW[(2 * cp + 1) * 64 + l]);
    }
}

// ---------------- X pre-pack in SORTED order: Xpk[pos][t][8] ---------------
__global__ void xprep_kernel(const float* __restrict__ ef, const float* __restrict__ st,
                             const int* __restrict__ lperm, uint* __restrict__ Xpk) {
    int idx = blockIdx.x * 256 + threadIdx.x;   // pos*8 + t
    int i = idx >> 3, t = idx & 7;
    int e = lperm[i];
    float v[16];
    #pragma unroll
    for (int f = 0; f < 15; ++f) v[f] = ef[(size_t)e * 120 + t * 15 + f];
    v[15] = st[(size_t)e * 8 + t];
    uint* dst = Xpk + (size_t)idx * 8;
    #pragma unroll
    for (int j = 0; j < 8; ++j) dst[j] = packh(v[2 * j], v[2 * j + 1]);
}

// ---------------- LSTM4: wave advances 4 length-sorted edges ---------------
// Lane = unit. Per weight chunk loaded (per-lane uint4), 4 edges consume it
// -> weight reload issue cost amortized 4x vs R11. h exchanged via per-wave
// LDS tile (uniform broadcast reads, conflict-free). Edge meta + x addresses
// are wave-uniform (scalarizable).

#define GSEL4(v4, i) ((i == 0) ? v4.x : (i == 1) ? v4.y : (i == 2) ? v4.z : v4.w)

__global__ __launch_bounds__(256)
void lstm4_kernel(const uint4* __restrict__ wpk4, const float* __restrict__ lb,
                  const uint* __restrict__ Xpk, const int* __restrict__ lperm,
                  const int* __restrict__ lenq, f16* __restrict__ hb)
{
    __shared__ __align__(16) f16 sH[4][4 * 64];   // [wave][edge][unit], 2 KB
    const int lane = threadIdx.x & 63;
    const int wv = threadIdx.x >> 6;

    const float b0 = lb[lane], b1 = lb[64 + lane], b2 = lb[128 + lane], b3 = lb[192 + lane];
    f16* myH = sH[wv];

    const int nT = Ec / 4;   // 80000 tiles of 4 sorted edges
    for (int tile = blockIdx.x * 4 + wv; tile < nT; tile += gridDim.x * 4) {
        const int p0 = tile * 4;
        const int oe0 = lperm[p0], oe1 = lperm[p0 + 1], oe2 = lperm[p0 + 2], oe3 = lperm[p0 + 3];
        const int l0 = lenq[p0], l1 = lenq[p0 + 1], l2 = lenq[p0 + 2], l3 = lenq[p0 + 3];
        const int tmax = max(max(l0, l1), max(l2, l3));

        const uint* xr = Xpk + (size_t)p0 * 64;   // sorted order: 4 edges contiguous

        float hA = 0.f, cA = 0.f, hB = 0.f, cB = 0.f;
        float hC = 0.f, cC = 0.f, hD = 0.f, cD = 0.f;

        for (int t = 0; t < tmax; ++t) {
            // x fragments (wave-uniform loads)
            uint4 xa0 = *(const uint4*)(xr + t * 8);
            uint4 xb0 = *(const uint4*)(xr + t * 8 + 4);
            uint4 xa1 = *(const uint4*)(xr + 64 + t * 8);
            uint4 xb1 = *(const uint4*)(xr + 64 + t * 8 + 4);
            uint4 xa2 = *(const uint4*)(xr + 128 + t * 8);
            uint4 xb2 = *(const uint4*)(xr + 128 + t * 8 + 4);
            uint4 xa3 = *(const uint4*)(xr + 192 + t * 8);
            uint4 xb3 = *(const uint4*)(xr + 192 + t * 8 + 4);

            float a0A = b0, a1A = b1, a2A = b2, a3A = b3;
            float a0B = b0, a1B = b1, a2B = b2, a3B = b3;
            float a0C = b0, a1C = b1, a2C = b2, a3C = b3;
            float a0D = b0, a1D = b1, a2D = b2, a3D = b3;

            // ---- x-part: 8 chunks, 1 weight load each, 16 dot2 per chunk ----
            #pragma unroll
            for (int k4 = 0; k4 < 8; ++k4) {
                uint4 w = wpk4[(32 + k4) * 64 + lane];
                uint xpA = (k4 < 4) ? GSEL4(xa0, k4) : GSEL4(xb0, (k4 - 4));
                uint xpB = (k4 < 4) ? GSEL4(xa1, k4) : GSEL4(xb1, (k4 - 4));
                uint xpC = (k4 < 4) ? GSEL4(xa2, k4) : GSEL4(xb2, (k4 - 4));
                uint xpD = (k4 < 4) ? GSEL4(xa3, k4) : GSEL4(xb3, (k4 - 4));
                a0A = dot2(w.x, xpA, a0A); a1A = dot2(w.y, xpA, a1A);
                a2A = dot2(w.z, xpA, a2A); a3A = dot2(w.w, xpA, a3A);
                a0B = dot2(w.x, xpB, a0B); a1B = dot2(w.y, xpB, a1B);
                a2B = dot2(w.z, xpB, a2B); a3B = dot2(w.w, xpB, a3B);
                a0C = dot2(w.x, xpC, a0C); a1C = dot2(w.y, xpC, a1C);
                a2C = dot2(w.z, xpC, a2C); a3C = dot2(w.w, xpC, a3C);
                a0D = dot2(w.x, xpD, a0D); a1D = dot2(w.y, xpD, a1D);
                a2D = dot2(w.z, xpD, a2D); a3D = dot2(w.w, xpD, a3D);
            }

            // ---- h-part: 8 h-chunks x 4 weight chunks, shared across edges ----
            if (t > 0) {
                #pragma unroll
                for (int jb = 0; jb < 8; ++jb) {
                    uint4 hA4 = *(const uint4*)(myH + 0 * 64 + jb * 8);
                    uint4 hB4 = *(const uint4*)(myH + 1 * 64 + jb * 8);
                    uint4 hC4 = *(const uint4*)(myH + 2 * 64 + jb * 8);
                    uint4 hD4 = *(const uint4*)(myH + 3 * 64 + jb * 8);
                    #pragma unroll
                    for (int i = 0; i < 4; ++i) {
                        uint4 w = wpk4[(jb * 4 + i) * 64 + lane];
                        uint hpA = GSEL4(hA4, i);
                        uint hpB = GSEL4(hB4, i);
                        uint hpC = GSEL4(hC4, i);
                        uint hpD = GSEL4(hD4, i);
                        a0A = dot2(w.x, hpA, a0A); a1A = dot2(w.y, hpA, a1A);
                        a2A = dot2(w.z, hpA, a2A); a3A = dot2(w.w, hpA, a3A);
                        a0B = dot2(w.x, hpB, a0B); a1B = dot2(w.y, hpB, a1B);
                        a2B = dot2(w.z, hpB, a2B); a3B = dot2(w.w, hpB, a3B);
                        a0C = dot2(w.x, hpC, a0C); a1C = dot2(w.y, hpC, a1C);
                        a2C = dot2(w.z, hpC, a2C); a3C = dot2(w.w, hpC, a3C);
                        a0D = dot2(w.x, hpD, a0D); a1D = dot2(w.y, hpD, a1D);
                        a2D = dot2(w.z, hpD, a2D); a3D = dot2(w.w, hpD, a3D);
                    }
                }
            }

            // ---- gates + state update (per-edge len mask) ----
            {
                float ig = sigm(a0A), fg = sigm(a1A), gg = tanh_(a2A), og = sigm(a3A);
                float cn = fg * cA + ig * gg, hn = og * tanh_(cn);
                if (t < l0) { cA = cn; hA = hn; }
                ig = sigm(a0B); fg = sigm(a1B); gg = tanh_(a2B); og = sigm(a3B);
                cn = fg * cB + ig * gg; hn = og * tanh_(cn);
                if (t < l1) { cB = cn; hB = hn; }
                ig = sigm(a0C); fg = sigm(a1C); gg = tanh_(a2C); og = sigm(a3C);
                cn = fg * cC + ig * gg; hn = og * tanh_(cn);
                if (t < l2) { cC = cn; hC = hn; }
                ig = sigm(a0D); fg = sigm(a1D); gg = tanh_(a2D); og = sigm(a3D);
                cn = fg * cD + ig * gg; hn = og * tanh_(cn);
                if (t < l3) { cD = cn; hD = hn; }
            }
            if (t + 1 < tmax) {
                myH[0 * 64 + lane] = (f16)hA;
                myH[1 * 64 + lane] = (f16)hB;
                myH[2 * 64 + lane] = (f16)hC;
                myH[3 * 64 + lane] = (f16)hD;
            }
        }

        hb[(size_t)oe0 * 64 + lane] = (f16)hA;
        hb[(size_t)oe1 * 64 + lane] = (f16)hB;
        hb[(size_t)oe2 * 64 + lane] = (f16)hC;
        hb[(size_t)oe3 * 64 + lane] = (f16)hD;
    }
}

// ---------------- MLP: wave-per-edge, eW in registers, f16 dot2 ------------
__global__ __launch_bounds__(256, 2)
void mlp_kernel(const float* __restrict__ nf, const float* __restrict__ pw,
                const uint4* __restrict__ ewc4, const float* __restrict__ ebias,
                const int* __restrict__ src, const f16* __restrict__ hb,
                f16* __restrict__ mbuf)
{
    __shared__ __align__(16) f16 sCat[4][192];
    const int lane = threadIdx.x & 63;
    const int wv = threadIdx.x >> 6;

    uint ew[24][4];
    #pragma unroll
    for (int i = 0; i < 24; ++i) {
        uint4 v = ewc4[i * 64 + lane];
        ew[i][0] = v.x; ew[i][1] = v.y; ew[i][2] = v.z; ew[i][3] = v.w;
    }
    const float pwl = pw[lane], pwh = pw[64 + lane];
    const float ebl = ebias[lane];

    f16* myCat = sCat[wv];
    const int wid = blockIdx.x * 4 + wv;
    const int stride = gridDim.x * 4;
    for (int e = wid; e < Ec; e += stride) {
        const int s = src[e];
        float hs0 = nf[(size_t)s * 128 + lane];
        float hs1 = nf[(size_t)s * 128 + 64 + lane];
        float part = hs0 * pwl + hs1 * pwh;
        #pragma unroll
        for (int off = 32; off; off >>= 1) part += __shfl_xor(part, off);
        float he = (float)hb[(size_t)e * 64 + lane];
        myCat[lane] = (f16)(hs0 - part * pwl);
        myCat[64 + lane] = (f16)(hs1 - part * pwh);
        myCat[128 + lane] = (f16)he;
        const uint4* cp = (const uint4*)myCat;
        float m0 = 0.f, m1 = 0.f, m2 = 0.f, m3 = 0.f;
        #pragma unroll
        for (int i = 0; i < 24; ++i) {
            uint4 q = cp[i];
            m0 = dot2(ew[i][0], q.x, m0);
            m1 = dot2(ew[i][1], q.y, m1);
            m2 = dot2(ew[i][2], q.z, m2);
            m3 = dot2(ew[i][3], q.w, m3);
        }
        float m = fmaxf(m0 + m1 + m2 + m3 + ebl, 0.f);
        mbuf[(size_t)e * 64 + lane] = (f16)m;
    }
}

// ---------------- Node kernel: segment-sum of m + node math ----------------
#define NB_WAVES 8
#define NB_THREADS (NB_WAVES * 64)
__global__ __launch_bounds__(NB_THREADS, 1)
void node_kernel(const float* __restrict__ nf,
                 const float* __restrict__ sgn,
                 const float* __restrict__ eW,
                 const float* __restrict__ ebias,
                 const float* __restrict__ nW,
                 const float* __restrict__ nbias,
                 const float* __restrict__ fcW,
                 const float* __restrict__ fcb,
                 const int* __restrict__ lnid,
                 const int* __restrict__ hist,
                 const int* __restrict__ perm,
                 const f16* __restrict__ m,
                 float* __restrict__ out,
                 int nWavesTotal)
{
    __shared__ float sEW[128 * 64];
    __shared__ float sNW[192 * 64];
    __shared__ float sFC[64 * 16];
    __shared__ float sCat[NB_WAVES][192];
    __shared__ float sAct[NB_WAVES][64];

    const int tid = threadIdx.x;
    for (int idx = tid; idx < 128 * 64; idx += NB_THREADS) sEW[idx] = eW[idx];
    for (int idx = tid; idx < 192 * 64; idx += NB_THREADS) sNW[idx] = nW[idx];
    for (int idx = tid; idx < 64 * 16; idx += NB_THREADS) sFC[idx] = fcW[idx];
    __syncthreads();

    const int lane = tid & 63;
    const int wv = tid >> 6;
    const int gwave = blockIdx.x * NB_WAVES + wv;

    const float ebv = ebias[lane];
    const float nbv = nbias[lane];
    const float fcbv = (lane < 16) ? fcb[lane] : 0.f;

    for (int n = gwave; n < N1c; n += nWavesTotal) {
        const int nid = lnid[n];
        float sh0 = nf[(size_t)nid * 128 + lane];
        float sh1 = nf[(size_t)nid * 128 + 64 + lane];
        sCat[wv][lane] = sh0;
        sCat[wv][64 + lane] = sh1;

        float tmp = ebv;
        #pragma unroll 8
        for (int cc = 0; cc < 128; ++cc) tmp += sCat[wv][cc] * sEW[cc * 64 + lane];

        const int o0 = (n == 0) ? 0 : hist[n - 1];
        const int o1 = hist[n];
        float av = 0.f;
        for (int base = o0; base < o1; base += 64) {
            int cnt = min(64, o1 - base);
            int pk = (lane < cnt) ? perm[base + lane] : 0;
            for (int j = 0; j < cnt; ++j) {
                int pe = __shfl(pk, j);
                av += (float)m[(size_t)pe * 64 + lane];
            }
        }

        float hu = (av - tmp) * sgn[n];
        sCat[wv][128 + lane] = hu;

        float acc = nbv;
        #pragma unroll 8
        for (int cc = 0; cc < 192; ++cc) acc += sCat[wv][cc] * sNW[cc * 64 + lane];
        acc = fmaxf(acc, 0.f);
        sAct[wv][lane] = acc;

        if (lane < 16) {
            float o = fcbv;
            #pragma unroll
            for (int j = 0; j < 64; ++j) o += sAct[wv][j] * sFC[j * 16 + lane];
            out[(size_t)n * 16 + lane] = o;
        }
    }
}

extern "C" void kernel_launch(void* const* d_in, const int* in_sizes, int n_in,
                              void* d_out, int out_size, void* d_ws, size_t ws_size,
                              hipStream_t stream) {
    const float* nf  = (const float*)d_in[0];
    const float* ef  = (const float*)d_in[1];
    const float* st  = (const float*)d_in[2];
    const float* sgn = (const float*)d_in[3];
    const float* pw  = (const float*)d_in[4];
    const float* Wih = (const float*)d_in[5];
    const float* Whh = (const float*)d_in[6];
    const float* lb  = (const float*)d_in[7];
    const float* eW  = (const float*)d_in[8];
    const float* eb  = (const float*)d_in[9];
    const float* nW  = (const float*)d_in[10];
    const float* nb  = (const float*)d_in[11];
    const float* fcW = (const float*)d_in[12];
    const float* fcb = (const float*)d_in[13];
    const int* elen = (const int*)d_in[14];
    const int* src  = (const int*)d_in[15];
    const int* dst  = (const int*)d_in[16];
    const int* lnid = (const int*)d_in[17];

    float* out = (float*)d_out;

    // ws layout (bytes)
    char* base = (char*)d_ws;
    int*  hist  = (int*) (base + 0);           // 80 KB
    int*  dperm = (int*) (base + 81920);       // -> 1392640
    int*  bc    = (int*) (base + 1392640);     // 16 KB
    int*  bo    = (int*) (base + 1409024);     // 16 KB
    int*  lperm = (int*) (base + 1425408);     // -> 2736128
    int*  lenq  = (int*) (base + 2736128);     // -> 4046848
    uint* wpk   = (uint*)(base + 4046848);     // 40 KB -> 4112384 (padded)
    uint* ewc   = (uint*)(base + 4112384);     // 24.5 KB -> 4145152
    uint* Xpk   = (uint*)(base + 4145152);     // 81.92 MB -> 86065152
    f16*  hb    = (f16*) (base + 86065152);    // 40.96 MB -> 127025152
    f16*  mbuf  = (f16*) (base + 127025152);   // 40.96 MB -> 167985152

    hipMemsetAsync(hist, 0, 81920, stream);

    // length sort (for lstm4 tiles + sorted Xpk)
    count_kernel<<<NBLK, 256, 0, stream>>>(elen, bc);
    offs_kernel<<<1, 256, 0, stream>>>(bc, bo);
    scatter2_kernel<<<NBLK, 256, 0, stream>>>(elen, bo, lperm, lenq);

    // dst sort (for node segment-sum)
    dhist_kernel<<<1250, 256, 0, stream>>>(dst, hist);
    dscan_kernel<<<1, 256, 0, stream>>>(hist);
    dscatter_kernel<<<1250, 256, 0, stream>>>(dst, hist, dperm);

    wprep_kernel<<<40, 256, 0, stream>>>(Whh, Wih, eW, wpk, ewc);
    xprep_kernel<<<10000, 256, 0, stream>>>(ef, st, lperm, Xpk);

    lstm4_kernel<<<2048, 256, 0, stream>>>((const uint4*)wpk, lb, Xpk, lperm, lenq, hb);

    mlp_kernel<<<1024, 256, 0, stream>>>(nf, pw, (const uint4*)ewc, eb, src, hb, mbuf);

    node_kernel<<<512, NB_THREADS, 0, stream>>>(
        nf, sgn, eW, eb, nW, nb, fcW, fcb, lnid, hist, dperm, mbuf, out,
        512 * NB_WAVES);
}

// Round 18
// 905.001 us; speedup vs baseline: 1.5285x; 1.0044x over previous
//
#include <hip/hip_runtime.h>

#define N0c 100000
#define N1c 20000
#define Ec 320000
#define NBLK ((Ec + 1023) / 1024)

typedef _Float16 f16;
typedef _Float16 f16x2 __attribute__((ext_vector_type(2)));

#define LOG2E 1.442695040888963f

__device__ __forceinline__ float tanh_(float x) {
    return 2.f * __builtin_amdgcn_rcpf(1.f + __builtin_amdgcn_exp2f(-2.f * LOG2E * x)) - 1.f;
}
__device__ __forceinline__ float dot2(uint w, uint v, float acc) {
#if __has_builtin(__builtin_amdgcn_fdot2)
    return __builtin_amdgcn_fdot2(__builtin_bit_cast(f16x2, w),
                                  __builtin_bit_cast(f16x2, v), acc, false);
#else
    f16x2 a = __builtin_bit_cast(f16x2, w);
    f16x2 b = __builtin_bit_cast(f16x2, v);
    return acc + (float)a[0] * (float)b[0] + (float)a[1] * (float)b[1];
#endif
}
__device__ __forceinline__ uint packh(float a, float b) {
    f16x2 p;
    p[0] = (f16)a;
    p[1] = (f16)b;
    return __builtin_bit_cast(uint, p);
}

// ---------------- length bucketing (deterministic counting sort) -----------
__global__ void count_kernel(const int* __restrict__ elen, int* __restrict__ bc) {
    __shared__ int h[8];
    if (threadIdx.x < 8) h[threadIdx.x] = 0;
    __syncthreads();
    const int base = blockIdx.x * 1024;
    for (int i = threadIdx.x; i < 1024; i += 256) {
        int e = base + i;
        if (e < Ec) atomicAdd(&h[elen[e] - 1], 1);
    }
    __syncthreads();
    if (threadIdx.x < 8) bc[blockIdx.x * 8 + threadIdx.x] = h[threadIdx.x];
}

__global__ void offs_kernel(const int* __restrict__ bc, int* __restrict__ bo) {
    __shared__ int s[NBLK * 8];
    __shared__ int base[8];
    const int tid = threadIdx.x;
    for (int i = tid; i < NBLK * 8; i += 256) s[i] = bc[i];
    __syncthreads();
    if (tid == 0) {
        int tot[8];
        for (int b = 0; b < 8; ++b) {
            int t = 0;
            for (int blk = 0; blk < NBLK; ++blk) t += s[blk * 8 + b];
            tot[b] = t;
        }
        int run = 0;
        for (int b = 0; b < 8; ++b) { base[b] = run; run += tot[b]; }
    }
    __syncthreads();
    if (tid < 8) {
        int run = base[tid];
        for (int blk = 0; blk < NBLK; ++blk) {
            int t = s[blk * 8 + tid];
            s[blk * 8 + tid] = run;
            run += t;
        }
    }
    __syncthreads();
    for (int i = tid; i < NBLK * 8; i += 256) bo[i] = s[i];
}

__global__ void scatter2_kernel(const int* __restrict__ elen, const int* __restrict__ bo,
                                int* __restrict__ lperm, int* __restrict__ lenq) {
    __shared__ int cnt[256][9];
    const int tid = threadIdx.x;
    const int base = blockIdx.x * 1024 + tid * 4;
    int lens[4];
    int lc0 = 0, lc1 = 0, lc2 = 0, lc3 = 0, lc4 = 0, lc5 = 0, lc6 = 0, lc7 = 0;
    #pragma unroll
    for (int j = 0; j < 4; ++j) {
        int e = base + j;
        int l = (e < Ec) ? elen[e] - 1 : -1;
        lens[j] = l;
        lc0 += (l == 0); lc1 += (l == 1); lc2 += (l == 2); lc3 += (l == 3);
        lc4 += (l == 4); lc5 += (l == 5); lc6 += (l == 6); lc7 += (l == 7);
    }
    cnt[tid][0] = lc0; cnt[tid][1] = lc1; cnt[tid][2] = lc2; cnt[tid][3] = lc3;
    cnt[tid][4] = lc4; cnt[tid][5] = lc5; cnt[tid][6] = lc6; cnt[tid][7] = lc7;
    __syncthreads();
    if (tid < 8) {
        int run = bo[blockIdx.x * 8 + tid];
        for (int i = 0; i < 256; ++i) {
            int t = cnt[i][tid];
            cnt[i][tid] = run;
            run += t;
        }
    }
    __syncthreads();
    #pragma unroll
    for (int b = 0; b < 8; ++b) {
        int p = cnt[tid][b];
        #pragma unroll
        for (int j = 0; j < 4; ++j) {
            if (lens[j] == b) { lperm[p] = base + j; lenq[p] = b + 1; ++p; }
        }
    }
}

// ---------------- dst bucketing (for node segment-sum) ---------------------
__global__ void dhist_kernel(const int* __restrict__ dst, int* __restrict__ hist) {
    int e = blockIdx.x * blockDim.x + threadIdx.x;
    if (e < Ec) atomicAdd(&hist[dst[e]], 1);
}

__global__ void dscan_kernel(int* __restrict__ hist) {
    __shared__ int s[N1c];
    __shared__ int psum[256];
    const int tid = threadIdx.x;
    const int CH = (N1c + 255) / 256;
    for (int i = tid; i < N1c; i += 256) s[i] = hist[i];
    __syncthreads();
    int loc = 0;
    #pragma unroll 1
    for (int j = 0; j < CH; ++j) {
        int i = tid * CH + j;
        if (i < N1c) loc += s[i];
    }
    psum[tid] = loc;
    __syncthreads();
    if (tid == 0) {
        int run = 0;
        for (int t = 0; t < 256; ++t) { int v = psum[t]; psum[t] = run; run += v; }
    }
    __syncthreads();
    int run = psum[tid];
    #pragma unroll 1
    for (int j = 0; j < CH; ++j) {
        int i = tid * CH + j;
        if (i < N1c) { int v = s[i]; s[i] = run; run += v; }
    }
    __syncthreads();
    for (int i = tid; i < N1c; i += 256) hist[i] = s[i];
}

__global__ void dscatter_kernel(const int* __restrict__ dst, int* __restrict__ cursor,
                                int* __restrict__ perm) {
    int e = blockIdx.x * blockDim.x + threadIdx.x;
    if (e < Ec) {
        int pos = atomicAdd(&cursor[dst[e]], 1);
        perm[pos] = e;
    }
}

// ---------------- weight prep: gate-pre-scaled packed f16 pairs ------------
// wpk[(r4*64+l)*4 + i]: gate i weights pre-scaled by s[i],
// s = {-LOG2E, -LOG2E, -2*LOG2E, -LOG2E}  (sigmoid / sigmoid / tanh / sigmoid)
__global__ void wprep_kernel(const float* __restrict__ Whh, const float* __restrict__ Wih,
                             const float* __restrict__ eW,
                             uint* __restrict__ wpk, uint* __restrict__ ewc) {
    int idx = blockIdx.x * 256 + threadIdx.x;
    if (idx < 40 * 256) {
        int r4 = idx >> 8, l = (idx >> 2) & 63, i = idx & 3;
        float s = (i == 2) ? (-2.f * LOG2E) : (-LOG2E);
        uint v;
        if (r4 < 32)
            v = packh(s * Whh[(2 * r4) * 256 + i * 64 + l],
                      s * Whh[(2 * r4 + 1) * 256 + i * 64 + l]);
        else {
            int kp = r4 - 32;
            v = packh(s * Wih[(2 * kp) * 256 + i * 64 + l],
                      s * Wih[(2 * kp + 1) * 256 + i * 64 + l]);
        }
        wpk[idx] = v;
    }
    if (idx < 24 * 256) {
        int c4 = idx >> 8, l = (idx >> 2) & 63, i = idx & 3;
        int cp = c4 * 4 + i;
        ewc[idx] = packh(eW[(2 * cp) * 64 + l], eW[(2 * cp + 1) * 64 + l]);
    }
}

// ---------------- X pre-pack in SORTED order: Xpk[pos][t][8] ---------------
__global__ void xprep_kernel(const float* __restrict__ ef, const float* __restrict__ st,
                             const int* __restrict__ lperm, uint* __restrict__ Xpk) {
    int idx = blockIdx.x * 256 + threadIdx.x;   // pos*8 + t
    int i = idx >> 3, t = idx & 7;
    int e = lperm[i];
    float v[16];
    #pragma unroll
    for (int f = 0; f < 15; ++f) v[f] = ef[(size_t)e * 120 + t * 15 + f];
    v[15] = st[(size_t)e * 8 + t];
    uint* dst = Xpk + (size_t)idx * 8;
    #pragma unroll
    for (int j = 0; j < 8; ++j) dst[j] = packh(v[2 * j], v[2 * j + 1]);
}

// ---------------- LSTM4: 4 length-sorted edges per wave --------------------
// R17 fix: h-part FIRST, then x-part with JIT wave-uniform x loads (SMEM) ->
// x words never live across the h-part, peak VGPR demand ~85 (was 116 with
// 32 x-words held across the step). Gate math pre-scaled at prep:
// sigmoid = rcp(1+exp2(acc)), g-tanh = 2*rcp(1+exp2(acc))-1.

#define GSEL4(v4, i) ((i == 0) ? v4.x : (i == 1) ? v4.y : (i == 2) ? v4.z : v4.w)

__global__ __launch_bounds__(256)
void lstm4_kernel(const uint4* __restrict__ wpk4, const float* __restrict__ lb,
                  const uint* __restrict__ Xpk, const int* __restrict__ lperm,
                  const int* __restrict__ lenq, f16* __restrict__ hb)
{
    __shared__ __align__(16) f16 sH[4][4 * 64];   // [wave][edge][unit], 2 KB
    const int lane = threadIdx.x & 63;
    const int wv = threadIdx.x >> 6;

    const float b0 = -LOG2E * lb[lane];
    const float b1 = -LOG2E * lb[64 + lane];
    const float b2 = -2.f * LOG2E * lb[128 + lane];
    const float b3 = -LOG2E * lb[192 + lane];
    f16* myH = sH[wv];

    const int nT = Ec / 4;   // 80000 tiles of 4 sorted edges
    for (int tile = blockIdx.x * 4 + wv; tile < nT; tile += gridDim.x * 4) {
        const int p0 = tile * 4;
        const int oe0 = lperm[p0], oe1 = lperm[p0 + 1], oe2 = lperm[p0 + 2], oe3 = lperm[p0 + 3];
        const int l0 = lenq[p0], l1 = lenq[p0 + 1], l2 = lenq[p0 + 2], l3 = lenq[p0 + 3];
        const int tmax = max(max(l0, l1), max(l2, l3));

        const uint* xr = Xpk + (size_t)p0 * 64;   // sorted order: 4 edges contiguous

        float hA = 0.f, cA = 0.f, hB = 0.f, cB = 0.f;
        float hC = 0.f, cC = 0.f, hD = 0.f, cD = 0.f;

        for (int t = 0; t < tmax; ++t) {
            float a0A = b0, a1A = b1, a2A = b2, a3A = b3;
            float a0B = b0, a1B = b1, a2B = b2, a3B = b3;
            float a0C = b0, a1C = b1, a2C = b2, a3C = b3;
            float a0D = b0, a1D = b1, a2D = b2, a3D = b3;

            // ---- h-part first (t>0): 8 h-chunks x 4 weight chunks ----
            if (t > 0) {
                #pragma unroll
                for (int jb = 0; jb < 8; ++jb) {
                    uint4 hA4 = *(const uint4*)(myH + 0 * 64 + jb * 8);
                    uint4 hB4 = *(const uint4*)(myH + 1 * 64 + jb * 8);
                    uint4 hC4 = *(const uint4*)(myH + 2 * 64 + jb * 8);
                    uint4 hD4 = *(const uint4*)(myH + 3 * 64 + jb * 8);
                    #pragma unroll
                    for (int i = 0; i < 4; ++i) {
                        uint4 w = wpk4[(jb * 4 + i) * 64 + lane];
                        uint hpA = GSEL4(hA4, i);
                        uint hpB = GSEL4(hB4, i);
                        uint hpC = GSEL4(hC4, i);
                        uint hpD = GSEL4(hD4, i);
                        a0A = dot2(w.x, hpA, a0A); a1A = dot2(w.y, hpA, a1A);
                        a2A = dot2(w.z, hpA, a2A); a3A = dot2(w.w, hpA, a3A);
                        a0B = dot2(w.x, hpB, a0B); a1B = dot2(w.y, hpB, a1B);
                        a2B = dot2(w.z, hpB, a2B); a3B = dot2(w.w, hpB, a3B);
                        a0C = dot2(w.x, hpC, a0C); a1C = dot2(w.y, hpC, a1C);
                        a2C = dot2(w.z, hpC, a2C); a3C = dot2(w.w, hpC, a3C);
                        a0D = dot2(w.x, hpD, a0D); a1D = dot2(w.y, hpD, a1D);
                        a2D = dot2(w.z, hpD, a2D); a3D = dot2(w.w, hpD, a3D);
                    }
                }
            }

            // ---- x-part: chunk-outer, shared w, JIT uniform x loads ----
            #pragma unroll
            for (int k4 = 0; k4 < 8; ++k4) {
                uint4 w = wpk4[(32 + k4) * 64 + lane];
                uint xA = xr[t * 8 + k4];
                uint xB = xr[64 + t * 8 + k4];
                uint xC = xr[128 + t * 8 + k4];
                uint xD = xr[192 + t * 8 + k4];
                a0A = dot2(w.x, xA, a0A); a1A = dot2(w.y, xA, a1A);
                a2A = dot2(w.z, xA, a2A); a3A = dot2(w.w, xA, a3A);
                a0B = dot2(w.x, xB, a0B); a1B = dot2(w.y, xB, a1B);
                a2B = dot2(w.z, xB, a2B); a3B = dot2(w.w, xB, a3B);
                a0C = dot2(w.x, xC, a0C); a1C = dot2(w.y, xC, a1C);
                a2C = dot2(w.z, xC, a2C); a3C = dot2(w.w, xC, a3C);
                a0D = dot2(w.x, xD, a0D); a1D = dot2(w.y, xD, a1D);
                a2D = dot2(w.z, xD, a2D); a3D = dot2(w.w, xD, a3D);
            }

            // ---- gates (pre-scaled) + state update (per-edge len mask) ----
            {
                float ig = __builtin_amdgcn_rcpf(1.f + __builtin_amdgcn_exp2f(a0A));
                float fg = __builtin_amdgcn_rcpf(1.f + __builtin_amdgcn_exp2f(a1A));
                float gg = 2.f * __builtin_amdgcn_rcpf(1.f + __builtin_amdgcn_exp2f(a2A)) - 1.f;
                float og = __builtin_amdgcn_rcpf(1.f + __builtin_amdgcn_exp2f(a3A));
                float cn = fg * cA + ig * gg, hn = og * tanh_(cn);
                if (t < l0) { cA = cn; hA = hn; }
                ig = __builtin_amdgcn_rcpf(1.f + __builtin_amdgcn_exp2f(a0B));
                fg = __builtin_amdgcn_rcpf(1.f + __builtin_amdgcn_exp2f(a1B));
                gg = 2.f * __builtin_amdgcn_rcpf(1.f + __builtin_amdgcn_exp2f(a2B)) - 1.f;
                og = __builtin_amdgcn_rcpf(1.f + __builtin_amdgcn_exp2f(a3B));
                cn = fg * cB + ig * gg; hn = og * tanh_(cn);
                if (t < l1) { cB = cn; hB = hn; }
                ig = __builtin_amdgcn_rcpf(1.f + __builtin_amdgcn_exp2f(a0C));
                fg = __builtin_amdgcn_rcpf(1.f + __builtin_amdgcn_exp2f(a1C));
                gg = 2.f * __builtin_amdgcn_rcpf(1.f + __builtin_amdgcn_exp2f(a2C)) - 1.f;
                og = __builtin_amdgcn_rcpf(1.f + __builtin_amdgcn_exp2f(a3C));
                cn = fg * cC + ig * gg; hn = og * tanh_(cn);
                if (t < l2) { cC = cn; hC = hn; }
                ig = __builtin_amdgcn_rcpf(1.f + __builtin_amdgcn_exp2f(a0D));
                fg = __builtin_amdgcn_rcpf(1.f + __builtin_amdgcn_exp2f(a1D));
                gg = 2.f * __builtin_amdgcn_rcpf(1.f + __builtin_amdgcn_exp2f(a2D)) - 1.f;
                og = __builtin_amdgcn_rcpf(1.f + __builtin_amdgcn_exp2f(a3D));
                cn = fg * cD + ig * gg; hn = og * tanh_(cn);
                if (t < l3) { cD = cn; hD = hn; }
            }
            if (t + 1 < tmax) {
                myH[0 * 64 + lane] = (f16)hA;
                myH[1 * 64 + lane] = (f16)hB;
                myH[2 * 64 + lane] = (f16)hC;
                myH[3 * 64 + lane] = (f16)hD;
            }
        }

        hb[(size_t)oe0 * 64 + lane] = (f16)hA;
        hb[(size_t)oe1 * 64 + lane] = (f16)hB;
        hb[(size_t)oe2 * 64 + lane] = (f16)hC;
        hb[(size_t)oe3 * 64 + lane] = (f16)hD;
    }
}

// ---------------- MLP: wave-per-edge, eW in registers, f16 dot2 ------------
__global__ __launch_bounds__(256, 2)
void mlp_kernel(const float* __restrict__ nf, const float* __restrict__ pw,
                const uint4* __restrict__ ewc4, const float* __restrict__ ebias,
                const int* __restrict__ src, const f16* __restrict__ hb,
                f16* __restrict__ mbuf)
{
    __shared__ __align__(16) f16 sCat[4][192];
    const int lane = threadIdx.x & 63;
    const int wv = threadIdx.x >> 6;

    uint ew[24][4];
    #pragma unroll
    for (int i = 0; i < 24; ++i) {
        uint4 v = ewc4[i * 64 + lane];
        ew[i][0] = v.x; ew[i][1] = v.y; ew[i][2] = v.z; ew[i][3] = v.w;
    }
    const float pwl = pw[lane], pwh = pw[64 + lane];
    const float ebl = ebias[lane];

    f16* myCat = sCat[wv];
    const int wid = blockIdx.x * 4 + wv;
    const int stride = gridDim.x * 4;
    for (int e = wid; e < Ec; e += stride) {
        const int s = src[e];
        float hs0 = nf[(size_t)s * 128 + lane];
        float hs1 = nf[(size_t)s * 128 + 64 + lane];
        float part = hs0 * pwl + hs1 * pwh;
        #pragma unroll
        for (int off = 32; off; off >>= 1) part += __shfl_xor(part, off);
        float he = (float)hb[(size_t)e * 64 + lane];
        myCat[lane] = (f16)(hs0 - part * pwl);
        myCat[64 + lane] = (f16)(hs1 - part * pwh);
        myCat[128 + lane] = (f16)he;
        const uint4* cp = (const uint4*)myCat;
        float m0 = 0.f, m1 = 0.f, m2 = 0.f, m3 = 0.f;
        #pragma unroll
        for (int i = 0; i < 24; ++i) {
            uint4 q = cp[i];
            m0 = dot2(ew[i][0], q.x, m0);
            m1 = dot2(ew[i][1], q.y, m1);
            m2 = dot2(ew[i][2], q.z, m2);
            m3 = dot2(ew[i][3], q.w, m3);
        }
        float m = fmaxf(m0 + m1 + m2 + m3 + ebl, 0.f);
        mbuf[(size_t)e * 64 + lane] = (f16)m;
    }
}

// ---------------- Node kernel: segment-sum of m + node math ----------------
#define NB_WAVES 8
#define NB_THREADS (NB_WAVES * 64)
__global__ __launch_bounds__(NB_THREADS, 1)
void node_kernel(const float* __restrict__ nf,
                 const float* __restrict__ sgn,
                 const float* __restrict__ eW,
                 const float* __restrict__ ebias,
                 const float* __restrict__ nW,
                 const float* __restrict__ nbias,
                 const float* __restrict__ fcW,
                 const float* __restrict__ fcb,
                 const int* __restrict__ lnid,
                 const int* __restrict__ hist,
                 const int* __restrict__ perm,
                 const f16* __restrict__ m,
                 float* __restrict__ out,
                 int nWavesTotal)
{
    __shared__ float sEW[128 * 64];
    __shared__ float sNW[192 * 64];
    __shared__ float sFC[64 * 16];
    __shared__ float sCat[NB_WAVES][192];
    __shared__ float sAct[NB_WAVES][64];

    const int tid = threadIdx.x;
    for (int idx = tid; idx < 128 * 64; idx += NB_THREADS) sEW[idx] = eW[idx];
    for (int idx = tid; idx < 192 * 64; idx += NB_THREADS) sNW[idx] = nW[idx];
    for (int idx = tid; idx < 64 * 16; idx += NB_THREADS) sFC[idx] = fcW[idx];
    __syncthreads();

    const int lane = tid & 63;
    const int wv = tid >> 6;
    const int gwave = blockIdx.x * NB_WAVES + wv;

    const float ebv = ebias[lane];
    const float nbv = nbias[lane];
    const float fcbv = (lane < 16) ? fcb[lane] : 0.f;

    for (int n = gwave; n < N1c; n += nWavesTotal) {
        const int nid = lnid[n];
        float sh0 = nf[(size_t)nid * 128 + lane];
        float sh1 = nf[(size_t)nid * 128 + 64 + lane];
        sCat[wv][lane] = sh0;
        sCat[wv][64 + lane] = sh1;

        float tmp = ebv;
        #pragma unroll 8
        for (int cc = 0; cc < 128; ++cc) tmp += sCat[wv][cc] * sEW[cc * 64 + lane];

        const int o0 = (n == 0) ? 0 : hist[n - 1];
        const int o1 = hist[n];
        float av = 0.f;
        for (int base = o0; base < o1; base += 64) {
            int cnt = min(64, o1 - base);
            int pk = (lane < cnt) ? perm[base + lane] : 0;
            for (int j = 0; j < cnt; ++j) {
                int pe = __shfl(pk, j);
                av += (float)m[(size_t)pe * 64 + lane];
            }
        }

        float hu = (av - tmp) * sgn[n];
        sCat[wv][128 + lane] = hu;

        float acc = nbv;
        #pragma unroll 8
        for (int cc = 0; cc < 192; ++cc) acc += sCat[wv][cc] * sNW[cc * 64 + lane];
        acc = fmaxf(acc, 0.f);
        sAct[wv][lane] = acc;

        if (lane < 16) {
            float o = fcbv;
            #pragma unroll
            for (int j = 0; j < 64; ++j) o += sAct[wv][j] * sFC[j * 16 + lane];
            out[(size_t)n * 16 + lane] = o;
        }
    }
}

extern "C" void kernel_launch(void* const* d_in, const int* in_sizes, int n_in,
                              void* d_out, int out_size, void* d_ws, size_t ws_size,
                              hipStream_t stream) {
    const float* nf  = (const float*)d_in[0];
    const float* ef  = (const float*)d_in[1];
    const float* st  = (const float*)d_in[2];
    const float* sgn = (const float*)d_in[3];
    const float* pw  = (const float*)d_in[4];
    const float* Wih = (const float*)d_in[5];
    const float* Whh = (const float*)d_in[6];
    const float* lb  = (const float*)d_in[7];
    const float* eW  = (const float*)d_in[8];
    const float* eb  = (const float*)d_in[9];
    const float* nW  = (const float*)d_in[10];
    const float* nb  = (const float*)d_in[11];
    const float* fcW = (const float*)d_in[12];
    const float* fcb = (const float*)d_in[13];
    const int* elen = (const int*)d_in[14];
    const int* src  = (const int*)d_in[15];
    const int* dst  = (const int*)d_in[16];
    const int* lnid = (const int*)d_in[17];

    float* out = (float*)d_out;

    // ws layout (bytes)
    char* base = (char*)d_ws;
    int*  hist  = (int*) (base + 0);           // 80 KB
    int*  dperm = (int*) (base + 81920);       // -> 1392640
    int*  bc    = (int*) (base + 1392640);     // 16 KB
    int*  bo    = (int*) (base + 1409024);     // 16 KB
    int*  lperm = (int*) (base + 1425408);     // -> 2736128
    int*  lenq  = (int*) (base + 2736128);     // -> 4046848
    uint* wpk   = (uint*)(base + 4046848);     // 40 KB -> 4112384 (padded)
    uint* ewc   = (uint*)(base + 4112384);     // 24.5 KB -> 4145152
    uint* Xpk   = (uint*)(base + 4145152);     // 81.92 MB -> 86065152
    f16*  hb    = (f16*) (base + 86065152);    // 40.96 MB -> 127025152
    f16*  mbuf  = (f16*) (base + 127025152);   // 40.96 MB -> 167985152

    hipMemsetAsync(hist, 0, 81920, stream);

    // length sort (for lstm4 tiles + sorted Xpk)
    count_kernel<<<NBLK, 256, 0, stream>>>(elen, bc);
    offs_kernel<<<1, 256, 0, stream>>>(bc, bo);
    scatter2_kernel<<<NBLK, 256, 0, stream>>>(elen, bo, lperm, lenq);

    // dst sort (for node segment-sum)
    dhist_kernel<<<1250, 256, 0, stream>>>(dst, hist);
    dscan_kernel<<<1, 256, 0, stream>>>(hist);
    dscatter_kernel<<<1250, 256, 0, stream>>>(dst, hist, dperm);

    wprep_kernel<<<40, 256, 0, stream>>>(Whh, Wih, eW, wpk, ewc);
    xprep_kernel<<<10000, 256, 0, stream>>>(ef, st, lperm, Xpk);

    lstm4_kernel<<<2048, 256, 0, stream>>>((const uint4*)wpk, lb, Xpk, lperm, lenq, hb);

    mlp_kernel<<<1024, 256, 0, stream>>>(nf, pw, (const uint4*)ewc, eb, src, hb, mbuf);

    node_kernel<<<512, NB_THREADS, 0, stream>>>(
        nf, sgn, eW, eb, nW, nb, fcW, fcb, lnid, hist, dperm, mbuf, out,
        512 * NB_WAVES);
}

// Round 19
// 866.862 us; speedup vs baseline: 1.5957x; 1.0440x over previous
//
#include <hip/hip_runtime.h>

#define N0c 100000
#define N1c 20000
#define Ec 320000
#define NBLK ((Ec + 1023) / 1024)

typedef _Float16 f16;
typedef _Float16 f16x2 __attribute__((ext_vector_type(2)));

#define LOG2E 1.442695040888963f

__device__ __forceinline__ float tanh_(float x) {
    return 2.f * __builtin_amdgcn_rcpf(1.f + __builtin_amdgcn_exp2f(-2.f * LOG2E * x)) - 1.f;
}
__device__ __forceinline__ float dot2(uint w, uint v, float acc) {
#if __has_builtin(__builtin_amdgcn_fdot2)
    return __builtin_amdgcn_fdot2(__builtin_bit_cast(f16x2, w),
                                  __builtin_bit_cast(f16x2, v), acc, false);
#else
    f16x2 a = __builtin_bit_cast(f16x2, w);
    f16x2 b = __builtin_bit_cast(f16x2, v);
    return acc + (float)a[0] * (float)b[0] + (float)a[1] * (float)b[1];
#endif
}
__device__ __forceinline__ uint packh(float a, float b) {
    f16x2 p;
    p[0] = (f16)a;
    p[1] = (f16)b;
    return __builtin_bit_cast(uint, p);
}

// ---------------- length bucketing (deterministic counting sort) -----------
__global__ void count_kernel(const int* __restrict__ elen, int* __restrict__ bc) {
    __shared__ int h[8];
    if (threadIdx.x < 8) h[threadIdx.x] = 0;
    __syncthreads();
    const int base = blockIdx.x * 1024;
    for (int i = threadIdx.x; i < 1024; i += 256) {
        int e = base + i;
        if (e < Ec) atomicAdd(&h[elen[e] - 1], 1);
    }
    __syncthreads();
    if (threadIdx.x < 8) bc[blockIdx.x * 8 + threadIdx.x] = h[threadIdx.x];
}

__global__ void offs_kernel(const int* __restrict__ bc, int* __restrict__ bo) {
    __shared__ int s[NBLK * 8];
    __shared__ int base[8];
    const int tid = threadIdx.x;
    for (int i = tid; i < NBLK * 8; i += 256) s[i] = bc[i];
    __syncthreads();
    if (tid == 0) {
        int tot[8];
        for (int b = 0; b < 8; ++b) {
            int t = 0;
            for (int blk = 0; blk < NBLK; ++blk) t += s[blk * 8 + b];
            tot[b] = t;
        }
        int run = 0;
        for (int b = 0; b < 8; ++b) { base[b] = run; run += tot[b]; }
    }
    __syncthreads();
    if (tid < 8) {
        int run = base[tid];
        for (int blk = 0; blk < NBLK; ++blk) {
            int t = s[blk * 8 + tid];
            s[blk * 8 + tid] = run;
            run += t;
        }
    }
    __syncthreads();
    for (int i = tid; i < NBLK * 8; i += 256) bo[i] = s[i];
}

__global__ void scatter2_kernel(const int* __restrict__ elen, const int* __restrict__ bo,
                                int* __restrict__ lperm, int* __restrict__ lenq) {
    __shared__ int cnt[256][9];
    const int tid = threadIdx.x;
    const int base = blockIdx.x * 1024 + tid * 4;
    int lens[4];
    int lc0 = 0, lc1 = 0, lc2 = 0, lc3 = 0, lc4 = 0, lc5 = 0, lc6 = 0, lc7 = 0;
    #pragma unroll
    for (int j = 0; j < 4; ++j) {
        int e = base + j;
        int l = (e < Ec) ? elen[e] - 1 : -1;
        lens[j] = l;
        lc0 += (l == 0); lc1 += (l == 1); lc2 += (l == 2); lc3 += (l == 3);
        lc4 += (l == 4); lc5 += (l == 5); lc6 += (l == 6); lc7 += (l == 7);
    }
    cnt[tid][0] = lc0; cnt[tid][1] = lc1; cnt[tid][2] = lc2; cnt[tid][3] = lc3;
    cnt[tid][4] = lc4; cnt[tid][5] = lc5; cnt[tid][6] = lc6; cnt[tid][7] = lc7;
    __syncthreads();
    if (tid < 8) {
        int run = bo[blockIdx.x * 8 + tid];
        for (int i = 0; i < 256; ++i) {
            int t = cnt[i][tid];
            cnt[i][tid] = run;
            run += t;
        }
    }
    __syncthreads();
    #pragma unroll
    for (int b = 0; b < 8; ++b) {
        int p = cnt[tid][b];
        #pragma unroll
        for (int j = 0; j < 4; ++j) {
            if (lens[j] == b) { lperm[p] = base + j; lenq[p] = b + 1; ++p; }
        }
    }
}

// ---------------- dst bucketing (for node segment-sum) ---------------------
__global__ void dhist_kernel(const int* __restrict__ dst, int* __restrict__ hist) {
    int e = blockIdx.x * blockDim.x + threadIdx.x;
    if (e < Ec) atomicAdd(&hist[dst[e]], 1);
}

__global__ void dscan_kernel(int* __restrict__ hist) {
    __shared__ int s[N1c];
    __shared__ int psum[256];
    const int tid = threadIdx.x;
    const int CH = (N1c + 255) / 256;
    for (int i = tid; i < N1c; i += 256) s[i] = hist[i];
    __syncthreads();
    int loc = 0;
    #pragma unroll 1
    for (int j = 0; j < CH; ++j) {
        int i = tid * CH + j;
        if (i < N1c) loc += s[i];
    }
    psum[tid] = loc;
    __syncthreads();
    if (tid == 0) {
        int run = 0;
        for (int t = 0; t < 256; ++t) { int v = psum[t]; psum[t] = run; run += v; }
    }
    __syncthreads();
    int run = psum[tid];
    #pragma unroll 1
    for (int j = 0; j < CH; ++j) {
        int i = tid * CH + j;
        if (i < N1c) { int v = s[i]; s[i] = run; run += v; }
    }
    __syncthreads();
    for (int i = tid; i < N1c; i += 256) hist[i] = s[i];
}

__global__ void dscatter_kernel(const int* __restrict__ dst, int* __restrict__ cursor,
                                int* __restrict__ perm) {
    int e = blockIdx.x * blockDim.x + threadIdx.x;
    if (e < Ec) {
        int pos = atomicAdd(&cursor[dst[e]], 1);
        perm[pos] = e;
    }
}

// ---------------- weight prep: gate-pre-scaled packed f16 pairs ------------
__global__ void wprep_kernel(const float* __restrict__ Whh, const float* __restrict__ Wih,
                             const float* __restrict__ eW,
                             uint* __restrict__ wpk, uint* __restrict__ ewc) {
    int idx = blockIdx.x * 256 + threadIdx.x;
    if (idx < 40 * 256) {
        int r4 = idx >> 8, l = (idx >> 2) & 63, i = idx & 3;
        float s = (i == 2) ? (-2.f * LOG2E) : (-LOG2E);
        uint v;
        if (r4 < 32)
            v = packh(s * Whh[(2 * r4) * 256 + i * 64 + l],
                      s * Whh[(2 * r4 + 1) * 256 + i * 64 + l]);
        else {
            int kp = r4 - 32;
            v = packh(s * Wih[(2 * kp) * 256 + i * 64 + l],
                      s * Wih[(2 * kp + 1) * 256 + i * 64 + l]);
        }
        wpk[idx] = v;
    }
    if (idx < 24 * 256) {
        int c4 = idx >> 8, l = (idx >> 2) & 63, i = idx & 3;
        int cp = c4 * 4 + i;
        ewc[idx] = packh(eW[(2 * cp) * 64 + l], eW[(2 * cp + 1) * 64 + l]);
    }
}

// ---------------- X pre-pack in SORTED order: Xpk[pos][t][8] ---------------
__global__ void xprep_kernel(const float* __restrict__ ef, const float* __restrict__ st,
                             const int* __restrict__ lperm, uint* __restrict__ Xpk) {
    int idx = blockIdx.x * 256 + threadIdx.x;   // pos*8 + t
    int i = idx >> 3, t = idx & 7;
    int e = lperm[i];
    float v[16];
    #pragma unroll
    for (int f = 0; f < 15; ++f) v[f] = ef[(size_t)e * 120 + t * 15 + f];
    v[15] = st[(size_t)e * 8 + t];
    uint* dst = Xpk + (size_t)idx * 8;
    #pragma unroll
    for (int j = 0; j < 8; ++j) dst[j] = packh(v[2 * j], v[2 * j + 1]);
}

// ---------------- LSTM4: 4 length-sorted edges per wave, weights in LDS ----
// R18 diagnosis: per wave-step the kernel re-read the whole 40 KB weight
// table from L2 (14.5 GB total = ~70% of L2 peak BW) -> L2-BW co-bound.
// Fix: stage wpk in LDS once per block; inner-loop weight reads become
// conflict-free ds_read_b128 (LDS BW ~2x L2, much lower latency).
// LDS/block = 40 KB weights + 2 KB sH -> 3 blocks/CU.

__global__ __launch_bounds__(256)
void lstm4_kernel(const uint4* __restrict__ wpk4, const float* __restrict__ lb,
                  const uint* __restrict__ Xpk, const int* __restrict__ lperm,
                  const int* __restrict__ lenq, f16* __restrict__ hb)
{
    __shared__ __align__(16) uint4 sW[2560];      // 40 KB: [chunk<40][lane]
    __shared__ __align__(16) f16 sH[4][4 * 64];   // [wave][edge][unit], 2 KB

    const int tid = threadIdx.x;
    #pragma unroll
    for (int i = 0; i < 10; ++i) sW[i * 256 + tid] = wpk4[i * 256 + tid];
    __syncthreads();

    const int lane = tid & 63;
    const int wv = tid >> 6;

    const float b0 = -LOG2E * lb[lane];
    const float b1 = -LOG2E * lb[64 + lane];
    const float b2 = -2.f * LOG2E * lb[128 + lane];
    const float b3 = -LOG2E * lb[192 + lane];
    f16* myH = sH[wv];
    const uint4* wl = sW + lane;   // chunk j at wl[j*64]

    const int nT = Ec / 4;
    for (int tile = blockIdx.x * 4 + wv; tile < nT; tile += gridDim.x * 4) {
        const int p0 = tile * 4;
        const int oe0 = lperm[p0], oe1 = lperm[p0 + 1], oe2 = lperm[p0 + 2], oe3 = lperm[p0 + 3];
        const int l0 = lenq[p0], l1 = lenq[p0 + 1], l2 = lenq[p0 + 2], l3 = lenq[p0 + 3];
        const int tmax = max(max(l0, l1), max(l2, l3));

        const uint* xr = Xpk + (size_t)p0 * 64;

        float hA = 0.f, cA = 0.f, hB = 0.f, cB = 0.f;
        float hC = 0.f, cC = 0.f, hD = 0.f, cD = 0.f;

        for (int t = 0; t < tmax; ++t) {
            float a0A = b0, a1A = b1, a2A = b2, a3A = b3;
            float a0B = b0, a1B = b1, a2B = b2, a3B = b3;
            float a0C = b0, a1C = b1, a2C = b2, a3C = b3;
            float a0D = b0, a1D = b1, a2D = b2, a3D = b3;

            // ---- h-part first (t>0): 8 h-chunks x 4 weight chunks ----
            if (t > 0) {
                #pragma unroll
                for (int jb = 0; jb < 8; ++jb) {
                    uint4 hA4 = *(const uint4*)(myH + 0 * 64 + jb * 8);
                    uint4 hB4 = *(const uint4*)(myH + 1 * 64 + jb * 8);
                    uint4 hC4 = *(const uint4*)(myH + 2 * 64 + jb * 8);
                    uint4 hD4 = *(const uint4*)(myH + 3 * 64 + jb * 8);
                    #pragma unroll
                    for (int i = 0; i < 4; ++i) {
                        uint4 w = wl[(jb * 4 + i) * 64];
                        uint hpA = (i == 0) ? hA4.x : (i == 1) ? hA4.y : (i == 2) ? hA4.z : hA4.w;
                        uint hpB = (i == 0) ? hB4.x : (i == 1) ? hB4.y : (i == 2) ? hB4.z : hB4.w;
                        uint hpC = (i == 0) ? hC4.x : (i == 1) ? hC4.y : (i == 2) ? hC4.z : hC4.w;
                        uint hpD = (i == 0) ? hD4.x : (i == 1) ? hD4.y : (i == 2) ? hD4.z : hD4.w;
                        a0A = dot2(w.x, hpA, a0A); a1A = dot2(w.y, hpA, a1A);
                        a2A = dot2(w.z, hpA, a2A); a3A = dot2(w.w, hpA, a3A);
                        a0B = dot2(w.x, hpB, a0B); a1B = dot2(w.y, hpB, a1B);
                        a2B = dot2(w.z, hpB, a2B); a3B = dot2(w.w, hpB, a3B);
                        a0C = dot2(w.x, hpC, a0C); a1C = dot2(w.y, hpC, a1C);
                        a2C = dot2(w.z, hpC, a2C); a3C = dot2(w.w, hpC, a3C);
                        a0D = dot2(w.x, hpD, a0D); a1D = dot2(w.y, hpD, a1D);
                        a2D = dot2(w.z, hpD, a2D); a3D = dot2(w.w, hpD, a3D);
                    }
                }
            }

            // ---- x-part: chunk-outer, shared w, JIT uniform x loads ----
            #pragma unroll
            for (int k4 = 0; k4 < 8; ++k4) {
                uint4 w = wl[(32 + k4) * 64];
                uint xA = xr[t * 8 + k4];
                uint xB = xr[64 + t * 8 + k4];
                uint xC = xr[128 + t * 8 + k4];
                uint xD = xr[192 + t * 8 + k4];
                a0A = dot2(w.x, xA, a0A); a1A = dot2(w.y, xA, a1A);
                a2A = dot2(w.z, xA, a2A); a3A = dot2(w.w, xA, a3A);
                a0B = dot2(w.x, xB, a0B); a1B = dot2(w.y, xB, a1B);
                a2B = dot2(w.z, xB, a2B); a3B = dot2(w.w, xB, a3B);
                a0C = dot2(w.x, xC, a0C); a1C = dot2(w.y, xC, a1C);
                a2C = dot2(w.z, xC, a2C); a3C = dot2(w.w, xC, a3C);
                a0D = dot2(w.x, xD, a0D); a1D = dot2(w.y, xD, a1D);
                a2D = dot2(w.z, xD, a2D); a3D = dot2(w.w, xD, a3D);
            }

            // ---- gates (pre-scaled) + state update (per-edge len mask) ----
            {
                float ig = __builtin_amdgcn_rcpf(1.f + __builtin_amdgcn_exp2f(a0A));
                float fg = __builtin_amdgcn_rcpf(1.f + __builtin_amdgcn_exp2f(a1A));
                float gg = 2.f * __builtin_amdgcn_rcpf(1.f + __builtin_amdgcn_exp2f(a2A)) - 1.f;
                float og = __builtin_amdgcn_rcpf(1.f + __builtin_amdgcn_exp2f(a3A));
                float cn = fg * cA + ig * gg, hn = og * tanh_(cn);
                if (t < l0) { cA = cn; hA = hn; }
                ig = __builtin_amdgcn_rcpf(1.f + __builtin_amdgcn_exp2f(a0B));
                fg = __builtin_amdgcn_rcpf(1.f + __builtin_amdgcn_exp2f(a1B));
                gg = 2.f * __builtin_amdgcn_rcpf(1.f + __builtin_amdgcn_exp2f(a2B)) - 1.f;
                og = __builtin_amdgcn_rcpf(1.f + __builtin_amdgcn_exp2f(a3B));
                cn = fg * cB + ig * gg; hn = og * tanh_(cn);
                if (t < l1) { cB = cn; hB = hn; }
                ig = __builtin_amdgcn_rcpf(1.f + __builtin_amdgcn_exp2f(a0C));
                fg = __builtin_amdgcn_rcpf(1.f + __builtin_amdgcn_exp2f(a1C));
                gg = 2.f * __builtin_amdgcn_rcpf(1.f + __builtin_amdgcn_exp2f(a2C)) - 1.f;
                og = __builtin_amdgcn_rcpf(1.f + __builtin_amdgcn_exp2f(a3C));
                cn = fg * cC + ig * gg; hn = og * tanh_(cn);
                if (t < l2) { cC = cn; hC = hn; }
                ig = __builtin_amdgcn_rcpf(1.f + __builtin_amdgcn_exp2f(a0D));
                fg = __builtin_amdgcn_rcpf(1.f + __builtin_amdgcn_exp2f(a1D));
                gg = 2.f * __builtin_amdgcn_rcpf(1.f + __builtin_amdgcn_exp2f(a2D)) - 1.f;
                og = __builtin_amdgcn_rcpf(1.f + __builtin_amdgcn_exp2f(a3D));
                cn = fg * cD + ig * gg; hn = og * tanh_(cn);
                if (t < l3) { cD = cn; hD = hn; }
            }
            if (t + 1 < tmax) {
                myH[0 * 64 + lane] = (f16)hA;
                myH[1 * 64 + lane] = (f16)hB;
                myH[2 * 64 + lane] = (f16)hC;
                myH[3 * 64 + lane] = (f16)hD;
            }
        }

        hb[(size_t)oe0 * 64 + lane] = (f16)hA;
        hb[(size_t)oe1 * 64 + lane] = (f16)hB;
        hb[(size_t)oe2 * 64 + lane] = (f16)hC;
        hb[(size_t)oe3 * 64 + lane] = (f16)hD;
    }
}

// ---------------- MLP: wave-per-edge, eW in registers, f16 dot2 ------------
__global__ __launch_bounds__(256, 2)
void mlp_kernel(const float* __restrict__ nf, const float* __restrict__ pw,
                const uint4* __restrict__ ewc4, const float* __restrict__ ebias,
                const int* __restrict__ src, const f16* __restrict__ hb,
                f16* __restrict__ mbuf)
{
    __shared__ __align__(16) f16 sCat[4][192];
    const int lane = threadIdx.x & 63;
    const int wv = threadIdx.x >> 6;

    uint ew[24][4];
    #pragma unroll
    for (int i = 0; i < 24; ++i) {
        uint4 v = ewc4[i * 64 + lane];
        ew[i][0] = v.x; ew[i][1] = v.y; ew[i][2] = v.z; ew[i][3] = v.w;
    }
    const float pwl = pw[lane], pwh = pw[64 + lane];
    const float ebl = ebias[lane];

    f16* myCat = sCat[wv];
    const int wid = blockIdx.x * 4 + wv;
    const int stride = gridDim.x * 4;
    for (int e = wid; e < Ec; e += stride) {
        const int s = src[e];
        float hs0 = nf[(size_t)s * 128 + lane];
        float hs1 = nf[(size_t)s * 128 + 64 + lane];
        float part = hs0 * pwl + hs1 * pwh;
        #pragma unroll
        for (int off = 32; off; off >>= 1) part += __shfl_xor(part, off);
        float he = (float)hb[(size_t)e * 64 + lane];
        myCat[lane] = (f16)(hs0 - part * pwl);
        myCat[64 + lane] = (f16)(hs1 - part * pwh);
        myCat[128 + lane] = (f16)he;
        const uint4* cp = (const uint4*)myCat;
        float m0 = 0.f, m1 = 0.f, m2 = 0.f, m3 = 0.f;
        #pragma unroll
        for (int i = 0; i < 24; ++i) {
            uint4 q = cp[i];
            m0 = dot2(ew[i][0], q.x, m0);
            m1 = dot2(ew[i][1], q.y, m1);
            m2 = dot2(ew[i][2], q.z, m2);
            m3 = dot2(ew[i][3], q.w, m3);
        }
        float m = fmaxf(m0 + m1 + m2 + m3 + ebl, 0.f);
        mbuf[(size_t)e * 64 + lane] = (f16)m;
    }
}

// ---------------- Node kernel: segment-sum of m + node math ----------------
#define NB_WAVES 8
#define NB_THREADS (NB_WAVES * 64)
__global__ __launch_bounds__(NB_THREADS, 1)
void node_kernel(const float* __restrict__ nf,
                 const float* __restrict__ sgn,
                 const float* __restrict__ eW,
                 const float* __restrict__ ebias,
                 const float* __restrict__ nW,
                 const float* __restrict__ nbias,
                 const float* __restrict__ fcW,
                 const float* __restrict__ fcb,
                 const int* __restrict__ lnid,
                 const int* __restrict__ hist,
                 const int* __restrict__ perm,
                 const f16* __restrict__ m,
                 float* __restrict__ out,
                 int nWavesTotal)
{
    __shared__ float sEW[128 * 64];
    __shared__ float sNW[192 * 64];
    __shared__ float sFC[64 * 16];
    __shared__ float sCat[NB_WAVES][192];
    __shared__ float sAct[NB_WAVES][64];

    const int tid = threadIdx.x;
    for (int idx = tid; idx < 128 * 64; idx += NB_THREADS) sEW[idx] = eW[idx];
    for (int idx = tid; idx < 192 * 64; idx += NB_THREADS) sNW[idx] = nW[idx];
    for (int idx = tid; idx < 64 * 16; idx += NB_THREADS) sFC[idx] = fcW[idx];
    __syncthreads();

    const int lane = tid & 63;
    const int wv = tid >> 6;
    const int gwave = blockIdx.x * NB_WAVES + wv;

    const float ebv = ebias[lane];
    const float nbv = nbias[lane];
    const float fcbv = (lane < 16) ? fcb[lane] : 0.f;

    for (int n = gwave; n < N1c; n += nWavesTotal) {
        const int nid = lnid[n];
        float sh0 = nf[(size_t)nid * 128 + lane];
        float sh1 = nf[(size_t)nid * 128 + 64 + lane];
        sCat[wv][lane] = sh0;
        sCat[wv][64 + lane] = sh1;

        float tmp = ebv;
        #pragma unroll 8
        for (int cc = 0; cc < 128; ++cc) tmp += sCat[wv][cc] * sEW[cc * 64 + lane];

        const int o0 = (n == 0) ? 0 : hist[n - 1];
        const int o1 = hist[n];
        float av = 0.f;
        for (int base = o0; base < o1; base += 64) {
            int cnt = min(64, o1 - base);
            int pk = (lane < cnt) ? perm[base + lane] : 0;
            for (int j = 0; j < cnt; ++j) {
                int pe = __shfl(pk, j);
                av += (float)m[(size_t)pe * 64 + lane];
            }
        }

        float hu = (av - tmp) * sgn[n];
        sCat[wv][128 + lane] = hu;

        float acc = nbv;
        #pragma unroll 8
        for (int cc = 0; cc < 192; ++cc) acc += sCat[wv][cc] * sNW[cc * 64 + lane];
        acc = fmaxf(acc, 0.f);
        sAct[wv][lane] = acc;

        if (lane < 16) {
            float o = fcbv;
            #pragma unroll
            for (int j = 0; j < 64; ++j) o += sAct[wv][j] * sFC[j * 16 + lane];
            out[(size_t)n * 16 + lane] = o;
        }
    }
}

extern "C" void kernel_launch(void* const* d_in, const int* in_sizes, int n_in,
                              void* d_out, int out_size, void* d_ws, size_t ws_size,
                              hipStream_t stream) {
    const float* nf  = (const float*)d_in[0];
    const float* ef  = (const float*)d_in[1];
    const float* st  = (const float*)d_in[2];
    const float* sgn = (const float*)d_in[3];
    const float* pw  = (const float*)d_in[4];
    const float* Wih = (const float*)d_in[5];
    const float* Whh = (const float*)d_in[6];
    const float* lb  = (const float*)d_in[7];
    const float* eW  = (const float*)d_in[8];
    const float* eb  = (const float*)d_in[9];
    const float* nW  = (const float*)d_in[10];
    const float* nb  = (const float*)d_in[11];
    const float* fcW = (const float*)d_in[12];
    const float* fcb = (const float*)d_in[13];
    const int* elen = (const int*)d_in[14];
    const int* src  = (const int*)d_in[15];
    const int* dst  = (const int*)d_in[16];
    const int* lnid = (const int*)d_in[17];

    float* out = (float*)d_out;

    // ws layout (bytes)
    char* base = (char*)d_ws;
    int*  hist  = (int*) (base + 0);           // 80 KB
    int*  dperm = (int*) (base + 81920);       // -> 1392640
    int*  bc    = (int*) (base + 1392640);     // 16 KB
    int*  bo    = (int*) (base + 1409024);     // 16 KB
    int*  lperm = (int*) (base + 1425408);     // -> 2736128
    int*  lenq  = (int*) (base + 2736128);     // -> 4046848
    uint* wpk   = (uint*)(base + 4046848);     // 40 KB -> 4112384 (padded)
    uint* ewc   = (uint*)(base + 4112384);     // 24.5 KB -> 4145152
    uint* Xpk   = (uint*)(base + 4145152);     // 81.92 MB -> 86065152
    f16*  hb    = (f16*) (base + 86065152);    // 40.96 MB -> 127025152
    f16*  mbuf  = (f16*) (base + 127025152);   // 40.96 MB -> 167985152

    hipMemsetAsync(hist, 0, 81920, stream);

    // length sort (for lstm4 tiles + sorted Xpk)
    count_kernel<<<NBLK, 256, 0, stream>>>(elen, bc);
    offs_kernel<<<1, 256, 0, stream>>>(bc, bo);
    scatter2_kernel<<<NBLK, 256, 0, stream>>>(elen, bo, lperm, lenq);

    // dst sort (for node segment-sum)
    dhist_kernel<<<1250, 256, 0, stream>>>(dst, hist);
    dscan_kernel<<<1, 256, 0, stream>>>(hist);
    dscatter_kernel<<<1250, 256, 0, stream>>>(dst, hist, dperm);

    wprep_kernel<<<40, 256, 0, stream>>>(Whh, Wih, eW, wpk, ewc);
    xprep_kernel<<<10000, 256, 0, stream>>>(ef, st, lperm, Xpk);

    lstm4_kernel<<<2048, 256, 0, stream>>>((const uint4*)wpk, lb, Xpk, lperm, lenq, hb);

    mlp_kernel<<<1024, 256, 0, stream>>>(nf, pw, (const uint4*)ewc, eb, src, hb, mbuf);

    node_kernel<<<512, NB_THREADS, 0, stream>>>(
        nf, sgn, eW, eb, nW, nb, fcW, fcb, lnid, hist, dperm, mbuf, out,
        512 * NB_WAVES);
}